// Round 10
// baseline (497.946 us; speedup 1.0000x reference)
//
#include <hip/hip_runtime.h>

typedef unsigned short u16;
typedef unsigned int u32;

typedef __attribute__((ext_vector_type(8))) short short8;
typedef __attribute__((ext_vector_type(4))) float floatx4;
typedef __attribute__((ext_vector_type(16))) float floatx16;
typedef __attribute__((ext_vector_type(2))) unsigned int uint2v;
typedef __attribute__((ext_vector_type(4))) unsigned int uint4v;

// ---------- bf16 helpers ----------
static __device__ __forceinline__ u16 f2b(float f) {
    union { float f; u32 i; } v; v.f = f;
    u32 r = v.i + 0x7fffu + ((v.i >> 16) & 1u);
    return (u16)(r >> 16);
}
// 2^x via v_exp_f32
static __device__ __forceinline__ float exp2f_hw(float x) {
    return __builtin_amdgcn_exp2f(x);
}
// pack two f32 -> bf16x2 dword (RNE) in one instruction
static __device__ __forceinline__ u32 cvtpk(float lo, float hi) {
    u32 r;
    asm("v_cvt_pk_bf16_f32 %0, %1, %2" : "=v"(r) : "v"(lo), "v"(hi));
    return r;
}

static __device__ __forceinline__ floatx4 mfma16(short8 a, short8 b, floatx4 c) {
    return __builtin_amdgcn_mfma_f32_16x16x32_bf16(a, b, c, 0, 0, 0);
}
static __device__ __forceinline__ floatx16 mfma32(short8 a, short8 b, floatx16 c) {
    return __builtin_amdgcn_mfma_f32_32x32x16_bf16(a, b, c, 0, 0, 0);
}

// async global->LDS, 16B per lane; LDS dest must be wave-uniform base (HW adds lane*16)
typedef __attribute__((address_space(1))) const void gas_void;
typedef __attribute__((address_space(3))) void las_void;
static __device__ __forceinline__ void gl_lds16(const void* g, void* l) {
    __builtin_amdgcn_global_load_lds((gas_void*)g, (las_void*)l, 16, 0, 0);
}

// counted vmcnt wait (T4) + raw barrier, both with compiler memory fence
template<int N> static __device__ __forceinline__ void vmw() {
    if constexpr (N == 0)      asm volatile("s_waitcnt vmcnt(0)" ::: "memory");
    else if constexpr (N == 2) asm volatile("s_waitcnt vmcnt(2)" ::: "memory");
    else if constexpr (N == 4) asm volatile("s_waitcnt vmcnt(4)" ::: "memory");
}
#define SBAR() asm volatile("s_barrier" ::: "memory")

#define B_ 4
#define S_ 2048
#define D_ 1024
#define H_ 16
#define DH_ 64
#define F_ 4096
#define QKVS 3072   // row stride of fused qkv output

// (1/8) * log2(e), folded into wq/bq so logits come out in exp2 domain
#define QSCALE 0.18033688011112042f

// ---------- mega-prep: cast_b + 6 weight transposes + concat_bias, ONE launch ----
// Launch-gap ~3-5us/kernel on this pipeline (measured: batching 4 transposes into
// 1 launch gained ~16us in r9); merge all prep into one dispatch. Block-uniform
// control flow per partition; parts are mutually independent.
// grid = 8192 (cast x->xb) + 4096 (wq/wk/wv/wo T) + 4096 (w1 T) + 4096 (w2 T)
//      + 12 (bias concat) = 20492 blocks of 256.
__global__ __launch_bounds__(256) void prep(
    const float* __restrict__ x, u16* __restrict__ xb,
    const float* __restrict__ wq, const float* __restrict__ wk,
    const float* __restrict__ wv, const float* __restrict__ wo,
    u16* __restrict__ wqkvT, u16* __restrict__ woT,
    const float* __restrict__ w1, u16* __restrict__ w1T,
    const float* __restrict__ w2, u16* __restrict__ w2T,
    const float* __restrict__ bq, const float* __restrict__ bk,
    const float* __restrict__ bv, float* __restrict__ qkvb) {
    int bid = blockIdx.x, tid = threadIdx.x;

    if (bid < 8192) {   // cast x (fp32) -> xb (bf16), 4 elems/thread, exact cover
        int id = bid * 256 + tid;
        float4 v = ((const float4*)x)[id];
        ushort4 u;
        u.x = f2b(v.x); u.y = f2b(v.y); u.z = f2b(v.z); u.w = f2b(v.w);
        ((ushort4*)xb)[id] = u;
        return;
    }
    bid -= 8192;

    if (bid >= 12288) { // concat + scale bias: [bq*QSCALE | bk | bv] (12 blocks)
        int i = (bid - 12288) * 256 + tid;
        float v;
        if (i < 1024) v = bq[i] * QSCALE;
        else if (i < 2048) v = bk[i - 1024];
        else v = bv[i - 2048];
        qkvb[i] = v;
        return;
    }

    // transpose+cast partitions (32x32 tile per block, 256 thr as 32x8)
    __shared__ float t[32][33];
    int x32 = tid & 31, y8 = tid >> 5;
    const float* in; u16* outp; float scale = 1.0f; int R, C, bx, by;
    if (bid < 4096) {          // four 1024x1024 weights
        int z = bid >> 10, rem = bid & 1023;
        bx = rem & 31; by = rem >> 5;
        in = (z == 0) ? wq : (z == 1) ? wk : (z == 2) ? wv : wo;
        outp = (z == 0) ? wqkvT : (z == 1) ? (wqkvT + 1024 * 1024)
             : (z == 2) ? (wqkvT + 2048 * 1024) : woT;
        scale = (z == 0) ? QSCALE : 1.0f;
        R = 1024; C = 1024;
    } else if (bid < 8192) {   // w1 [1024 x 4096]
        int rem = bid - 4096; bx = rem & 127; by = rem >> 7;
        in = w1; outp = w1T; R = 1024; C = 4096;
    } else {                   // w2 [4096 x 1024]
        int rem = bid - 8192; bx = rem & 31; by = rem >> 5;
        in = w2; outp = w2T; R = 4096; C = 1024;
    }
#pragma unroll
    for (int i = 0; i < 4; ++i) {
        int r = by * 32 + y8 + i * 8;
        t[y8 + i * 8][x32] = in[(size_t)r * C + bx * 32 + x32];
    }
    __syncthreads();
#pragma unroll
    for (int i = 0; i < 4; ++i) {
        int c = bx * 32 + y8 + i * 8;
        outp[(size_t)c * R + by * 32 + x32] = f2b(t[x32][y8 + i * 8] * scale);
    }
}

// ---------- transpose V: qkv[B*S, 3072] cols 2048.. -> vt [B,H,DH,S] bf16 ----------
__global__ void transpose_v(const u16* __restrict__ qkv, u16* __restrict__ vt) {
    __shared__ u16 t[32][33];
    int bh = blockIdx.z; int b = bh >> 4, h = bh & 15;
    int s0 = blockIdx.x * 32, d0 = blockIdx.y * 32;
    int x = threadIdx.x, y = threadIdx.y;  // 32x8
#pragma unroll
    for (int i = 0; i < 4; ++i)
        t[y + i * 8][x] =
            qkv[(size_t)(b * S_ + s0 + y + i * 8) * QKVS + 2048 + h * DH_ + d0 + x];
    __syncthreads();
#pragma unroll
    for (int i = 0; i < 4; ++i)
        vt[((size_t)bh * DH_ + d0 + y + i * 8) * S_ + s0 + x] = t[x][y + i * 8];
}

// ---------- gemm256 v4: 256x256 tile, 8-phase, slot-disciplined staging ----------
// (see round-7 comments: WAR-safe 3-5-phase prefetch distance, vmcnt(2) at
// ph4/ph8 only, one barrier per phase, XOR-swizzled 8KB chunks, split-K via z)
#define MFMA16X(MH)                                                        \
    __builtin_amdgcn_s_setprio(1);                                         \
    acc[(MH)*4+0][0] = mfma16(af0, bf0, acc[(MH)*4+0][0]);                 \
    acc[(MH)*4+0][1] = mfma16(af0, bf1, acc[(MH)*4+0][1]);                 \
    acc[(MH)*4+0][2] = mfma16(af0, bf2, acc[(MH)*4+0][2]);                 \
    acc[(MH)*4+0][3] = mfma16(af0, bf3, acc[(MH)*4+0][3]);                 \
    acc[(MH)*4+1][0] = mfma16(af1, bf0, acc[(MH)*4+1][0]);                 \
    acc[(MH)*4+1][1] = mfma16(af1, bf1, acc[(MH)*4+1][1]);                 \
    acc[(MH)*4+1][2] = mfma16(af1, bf2, acc[(MH)*4+1][2]);                 \
    acc[(MH)*4+1][3] = mfma16(af1, bf3, acc[(MH)*4+1][3]);                 \
    acc[(MH)*4+2][0] = mfma16(af2, bf0, acc[(MH)*4+2][0]);                 \
    acc[(MH)*4+2][1] = mfma16(af2, bf1, acc[(MH)*4+2][1]);                 \
    acc[(MH)*4+2][2] = mfma16(af2, bf2, acc[(MH)*4+2][2]);                 \
    acc[(MH)*4+2][3] = mfma16(af2, bf3, acc[(MH)*4+2][3]);                 \
    acc[(MH)*4+3][0] = mfma16(af3, bf0, acc[(MH)*4+3][0]);                 \
    acc[(MH)*4+3][1] = mfma16(af3, bf1, acc[(MH)*4+3][1]);                 \
    acc[(MH)*4+3][2] = mfma16(af3, bf2, acc[(MH)*4+3][2]);                 \
    acc[(MH)*4+3][3] = mfma16(af3, bf3, acc[(MH)*4+3][3]);                 \
    __builtin_amdgcn_s_setprio(0);

#define PPAIR(P, KH, STa, Wa, STb, Wb) {                                   \
    int ro = l * 64 + ((((KH) * 4 + quad) ^ l7) << 3);                     \
    const u16* bBp = &smem[32768 + (P) * 16384 + wc * 4096];               \
    short8 bf0 = *(const short8*)&bBp[ro];                                 \
    short8 bf1 = *(const short8*)&bBp[ro + 1024];                          \
    short8 bf2 = *(const short8*)&bBp[ro + 2048];                          \
    short8 bf3 = *(const short8*)&bBp[ro + 3072];                          \
    {   const u16* bAp = &smem[(P) * 16384 + (wr * 2 + 0) * 4096];         \
        short8 af0 = *(const short8*)&bAp[ro];                             \
        short8 af1 = *(const short8*)&bAp[ro + 1024];                      \
        short8 af2 = *(const short8*)&bAp[ro + 2048];                      \
        short8 af3 = *(const short8*)&bAp[ro + 3072];                      \
        STa; Wa;                                                           \
        MFMA16X(0)                                                         \
        SBAR();                                                            \
    }                                                                      \
    {   const u16* bAp = &smem[(P) * 16384 + (wr * 2 + 1) * 4096];         \
        short8 af0 = *(const short8*)&bAp[ro];                             \
        short8 af1 = *(const short8*)&bAp[ro + 1024];                      \
        short8 af2 = *(const short8*)&bAp[ro + 2048];                      \
        short8 af3 = *(const short8*)&bAp[ro + 3072];                      \
        STb; Wb;                                                           \
        MFMA16X(1)                                                         \
        SBAR();                                                            \
    } }

__global__ __launch_bounds__(512) void gemm256(const u16* __restrict__ A,
                                               const u16* __restrict__ Bt,
                                               const float* __restrict__ bias,
                                               float* __restrict__ outF,
                                               float* __restrict__ outF2,
                                               u16* __restrict__ outB,
                                               int M, int N, int K, int klen,
                                               int relu) {
    __shared__ __align__(16) u16 smem[65536];   // 128 KB

    int tid = threadIdx.x;
    int w = tid >> 6, lane = tid & 63, quad = lane >> 4, l = lane & 15;
    int wr = w >> 2, wc = w & 3;
    int l7 = l & 7;

    // XCD-aware bijective block swizzle (nwg % 8 == 0 for all our shapes)
    int nbN = gridDim.x, nwg = gridDim.x * gridDim.y;
    int flat = blockIdx.y * gridDim.x + blockIdx.x;
    int swz = (flat & 7) * (nwg >> 3) + (flat >> 3);
    int bM = swz / nbN, bN = swz % nbN;
    int koff = blockIdx.z * klen;

    floatx4 acc[8][4];
#pragma unroll
    for (int i = 0; i < 8; ++i)
#pragma unroll
        for (int j = 0; j < 4; ++j) acc[i][j] = (floatx4){0.f, 0.f, 0.f, 0.f};

    int rT = tid >> 3, cT = tid & 7;
    int cg8 = ((cT ^ (rT & 7)) << 3);
    const u16* gA0 = A + (size_t)(bM * 256 + rT) * K + koff + cg8;
    const u16* gB0 = Bt + (size_t)(bN * 256 + rT) * K + koff + cg8;

    auto stA = [&](int p, int ch, int t) {
        gl_lds16(gA0 + (size_t)(ch * 64) * K + t * 64,
                 (void*)&smem[p * 16384 + ch * 4096 + (w << 9)]);
    };
    auto stB = [&](int p, int hb, int t) {
        gl_lds16(gB0 + (size_t)(hb * 64) * K + t * 64,
                 (void*)&smem[32768 + p * 16384 + hb * 4096 + (w << 9)]);
    };

    // prologue: tile0 full -> P0, tile1 {A0,A2} -> P1; drain t0 (leave t1's 2)
    stA(0, 0, 0); stA(0, 1, 0); stA(0, 2, 0); stA(0, 3, 0);
    stB(0, 0, 0); stB(0, 1, 0); stB(0, 2, 0); stB(0, 3, 0);
    stA(1, 0, 1); stA(1, 2, 1);
    vmw<2>(); SBAR();

    const int NI = klen >> 7;   // iterations of 2 K-tiles
    for (int j = 0; j < NI - 1; ++j) {
        int to = 2 * j + 1, te = 2 * j + 2, tn = 2 * j + 3;
        PPAIR(0, 0, (stA(1,1,to), stA(1,3,to), stB(1,0,to), stB(1,1,to)), ((void)0),
                    (stB(1,2,to), stB(1,3,to)), ((void)0))
        PPAIR(0, 1, ((void)0), ((void)0),
                    (stA(0,0,te), stA(0,2,te)), vmw<2>())
        PPAIR(1, 0, (stA(0,1,te), stA(0,3,te), stB(0,0,te), stB(0,1,te)), ((void)0),
                    (stB(0,2,te), stB(0,3,te)), ((void)0))
        PPAIR(1, 1, ((void)0), ((void)0),
                    (stA(1,0,tn), stA(1,2,tn)), vmw<2>())
    }
    {   // final iteration: finish P1<-KT-1 at ph1/ph2, drain all at ph4
        int to = 2 * (NI - 1) + 1;
        PPAIR(0, 0, (stA(1,1,to), stA(1,3,to), stB(1,0,to), stB(1,1,to)), ((void)0),
                    (stB(1,2,to), stB(1,3,to)), ((void)0))
        PPAIR(0, 1, ((void)0), ((void)0), ((void)0), vmw<0>())
        PPAIR(1, 0, ((void)0), ((void)0), ((void)0), ((void)0))
        PPAIR(1, 1, ((void)0), ((void)0), ((void)0), ((void)0))
    }

    // epilogue: row-major store order (nt innermost); bias hoisted
    float* of = (blockIdx.z == 0) ? outF : outF2;
    const float* bp = (blockIdx.z == 0) ? bias : nullptr;
    float bv4[4];
#pragma unroll
    for (int nt = 0; nt < 4; ++nt) {
        int colg = bN * 256 + wc * 64 + nt * 16 + l;
        bv4[nt] = bp ? bp[colg] : 0.f;
    }
#pragma unroll
    for (int mt = 0; mt < 8; ++mt) {
#pragma unroll
        for (int rr = 0; rr < 4; ++rr) {
            int rowg = bM * 256 + wr * 128 + mt * 16 + quad * 4 + rr;
            size_t rb = (size_t)rowg * N + bN * 256 + wc * 64 + l;
#pragma unroll
            for (int nt = 0; nt < 4; ++nt) {
                float v = acc[mt][nt][rr] + bv4[nt];
                if (relu) v = fmaxf(v, 0.f);
                if (of) of[rb + nt * 16] = v;
                if (outB) outB[rb + nt * 16] = f2b(v);
            }
        }
    }
}

// ---------- flash attention v7b: v7 + KVBLK=128 (halved barrier count) ----------
// v7 structure (64 q/wave shared-frag reads, swapped QK^T, in-register P via
// cvt_pk + permlane32_swap) kept verbatim; the only change is processing TWO
// 64-key halves per __syncthreads (KVBLK 64 -> 128): barriers 32 -> 16 per
// block, each DMA batch (8 issues) gets a 2x compute window before the drain.
// LDS 64 KB -> still 2 blocks/CU. Grid (B*H, S/256).
#define PACK8(sv, rb, dst) {                                                   \
    u32 pa_ = cvtpk(sv[rb + 0], sv[rb + 1]), pb_ = cvtpk(sv[rb + 4], sv[rb + 5]); \
    u32 pc_ = cvtpk(sv[rb + 2], sv[rb + 3]), pd_ = cvtpk(sv[rb + 6], sv[rb + 7]); \
    uint2v t0_ = __builtin_amdgcn_permlane32_swap(pa_, pb_, 0, 0);             \
    uint2v t1_ = __builtin_amdgcn_permlane32_swap(pc_, pd_, 0, 0);             \
    union { uint4v u; short8 s8; } cv_;                                        \
    cv_.u = (uint4v){t0_[0], t1_[0], t0_[1], t1_[1]};                          \
    dst = cv_.s8; }

__global__ __launch_bounds__(256, 2) void attn_kernel(const u16* __restrict__ qkv,
                                                      const u16* __restrict__ vt,
                                                      u16* __restrict__ ctx) {
    __shared__ __align__(16) u16 Kb[2][128 * 64];   // 32 KB
    __shared__ __align__(16) u16 Vb[2][128 * 64];   // 32 KB

    int bh = blockIdx.x; int b = bh >> 4, h = bh & 15;
    int tid = threadIdx.x;
    int w = tid >> 6, lane = tid & 63;
    int l32 = lane & 31, hi = lane >> 5, row7 = lane & 7;
    int qw = blockIdx.y * 256 + w * 64;  // this wave's first q-row (64 rows/wave)

    int r = lane >> 3, c = lane & 7;
    int cs = ((c ^ r) << 3);
    const u16* gK0 = qkv + (size_t)(b * S_ + w * 16 + r) * QKVS + 1024 + h * DH_ + cs;
    const u16* gK1 = gK0 + (size_t)8 * QKVS;
    const u16* gV0 = vt + (size_t)(bh * DH_ + w * 16 + r) * S_ + cs;
    const u16* gV1 = gV0 + (size_t)8 * S_;

    // stage one 64-key half into buffer bb, half hh; advances pointers 64 keys
    auto stage = [&](int bb, int hh) {
        u16* lk = &Kb[bb][hh * 4096 + w * 16 * 64];
        u16* lv = &Vb[bb][hh * 4096 + w * 16 * 64];
        gl_lds16(gK0, lk);
        gl_lds16(gK1, lk + 8 * 64);
        gl_lds16(gV0, lv);
        gl_lds16(gV1, lv + 8 * 64);
        gK0 += (size_t)64 * QKVS; gK1 += (size_t)64 * QKVS;
        gV0 += 64; gV1 += 64;
    };

    // Q B-fragments for both subtiles: B[n = q][k = kc*16 + hi*8 + j]
    short8 qa0, qa1, qa2, qa3, qb0, qb1, qb2, qb3;
    {
        const u16* qpA = qkv + (size_t)(b * S_ + qw + l32) * QKVS + h * DH_ + hi * 8;
        qa0 = *(const short8*)(qpA);
        qa1 = *(const short8*)(qpA + 16);
        qa2 = *(const short8*)(qpA + 32);
        qa3 = *(const short8*)(qpA + 48);
        const u16* qpB = qpA + (size_t)32 * QKVS;
        qb0 = *(const short8*)(qpB);
        qb1 = *(const short8*)(qpB + 16);
        qb2 = *(const short8*)(qpB + 32);
        qb3 = *(const short8*)(qpB + 48);
    }

    floatx16 OA0, OA1, OB0, OB1;
#pragma unroll
    for (int i = 0; i < 16; ++i) { OA0[i] = 0.f; OA1[i] = 0.f; OB0[i] = 0.f; OB1[i] = 0.f; }
    float lra0 = 0.f, lra1 = 0.f, lrb0 = 0.f, lrb1 = 0.f;  // denominator partials

    int roff0 = l32 * 64;
    int roff1 = (32 + l32) * 64;

    stage(0, 0); stage(0, 1);
    __syncthreads();

    const int NT = S_ / 128;   // 16 iterations of 128 keys
    for (int kt = 0; kt < NT; ++kt) {
        int cur = kt & 1;
        if (kt + 1 < NT) { stage(cur ^ 1, 0); stage(cur ^ 1, 1); }

#pragma unroll
        for (int hh = 0; hh < 2; ++hh) {
            const u16* Kc = &Kb[cur][hh * 4096];
            const u16* Vc = &Vb[cur][hh * 4096];

            short8 paA0, paA1, paA2, paA3, paB0, paB1, paB2, paB3;

            // ---- S^T tile 0 (keys 0..31 of half): K frag feeds both q-subtiles --
            {
                floatx16 sA, sB;
#pragma unroll
                for (int i = 0; i < 16; ++i) { sA[i] = 0.f; sB[i] = 0.f; }
#pragma unroll
                for (int kc = 0; kc < 4; ++kc) {
                    int ch = (((kc * 2 + hi) ^ row7) << 3);
                    short8 ka = *(const short8*)&Kc[roff0 + ch];
                    short8 qkA = (kc == 0) ? qa0 : (kc == 1) ? qa1 : (kc == 2) ? qa2 : qa3;
                    short8 qkB = (kc == 0) ? qb0 : (kc == 1) ? qb1 : (kc == 2) ? qb2 : qb3;
                    sA = mfma32(ka, qkA, sA);
                    sB = mfma32(ka, qkB, sB);
                }
#pragma unroll
                for (int i = 0; i < 16; ++i) { sA[i] = exp2f_hw(sA[i]); sB[i] = exp2f_hw(sB[i]); }
#pragma unroll
                for (int i = 0; i < 16; i += 4) {
                    lra0 += sA[i + 0] + sA[i + 1];
                    lra1 += sA[i + 2] + sA[i + 3];
                    lrb0 += sB[i + 0] + sB[i + 1];
                    lrb1 += sB[i + 2] + sB[i + 3];
                }
                PACK8(sA, 0, paA0); PACK8(sA, 8, paA1);
                PACK8(sB, 0, paB0); PACK8(sB, 8, paB1);
            }

            // ---- S^T tile 1 (keys 32..63 of half) ----
            {
                floatx16 sA, sB;
#pragma unroll
                for (int i = 0; i < 16; ++i) { sA[i] = 0.f; sB[i] = 0.f; }
#pragma unroll
                for (int kc = 0; kc < 4; ++kc) {
                    int ch = (((kc * 2 + hi) ^ row7) << 3);
                    short8 ka = *(const short8*)&Kc[roff1 + ch];
                    short8 qkA = (kc == 0) ? qa0 : (kc == 1) ? qa1 : (kc == 2) ? qa2 : qa3;
                    short8 qkB = (kc == 0) ? qb0 : (kc == 1) ? qb1 : (kc == 2) ? qb2 : qb3;
                    sA = mfma32(ka, qkA, sA);
                    sB = mfma32(ka, qkB, sB);
                }
#pragma unroll
                for (int i = 0; i < 16; ++i) { sA[i] = exp2f_hw(sA[i]); sB[i] = exp2f_hw(sB[i]); }
#pragma unroll
                for (int i = 0; i < 16; i += 4) {
                    lra0 += sA[i + 0] + sA[i + 1];
                    lra1 += sA[i + 2] + sA[i + 3];
                    lrb0 += sB[i + 0] + sB[i + 1];
                    lrb1 += sB[i + 2] + sB[i + 3];
                }
                PACK8(sA, 0, paA2); PACK8(sA, 8, paA3);
                PACK8(sB, 0, paB2); PACK8(sB, 8, paB3);
            }

            // ---- O += P @ V: each V frag feeds both q-subtiles ----
            {   // dh 0..31
                short8 vb0 = *(const short8*)&Vc[roff0 + (((0 + hi) ^ row7) << 3)];
                OA0 = mfma32(paA0, vb0, OA0);
                OB0 = mfma32(paB0, vb0, OB0);
                short8 vb1 = *(const short8*)&Vc[roff0 + (((2 + hi) ^ row7) << 3)];
                OA0 = mfma32(paA1, vb1, OA0);
                OB0 = mfma32(paB1, vb1, OB0);
                short8 vb2 = *(const short8*)&Vc[roff0 + (((4 + hi) ^ row7) << 3)];
                OA0 = mfma32(paA2, vb2, OA0);
                OB0 = mfma32(paB2, vb2, OB0);
                short8 vb3 = *(const short8*)&Vc[roff0 + (((6 + hi) ^ row7) << 3)];
                OA0 = mfma32(paA3, vb3, OA0);
                OB0 = mfma32(paB3, vb3, OB0);
            }
            {   // dh 32..63
                short8 vb0 = *(const short8*)&Vc[roff1 + (((0 + hi) ^ row7) << 3)];
                OA1 = mfma32(paA0, vb0, OA1);
                OB1 = mfma32(paB0, vb0, OB1);
                short8 vb1 = *(const short8*)&Vc[roff1 + (((2 + hi) ^ row7) << 3)];
                OA1 = mfma32(paA1, vb1, OA1);
                OB1 = mfma32(paB1, vb1, OB1);
                short8 vb2 = *(const short8*)&Vc[roff1 + (((4 + hi) ^ row7) << 3)];
                OA1 = mfma32(paA2, vb2, OA1);
                OB1 = mfma32(paB2, vb2, OB1);
                short8 vb3 = *(const short8*)&Vc[roff1 + (((6 + hi) ^ row7) << 3)];
                OA1 = mfma32(paA3, vb3, OA1);
                OB1 = mfma32(paB3, vb3, OB1);
            }
        }

        __syncthreads();  // drains gl_lds (vmcnt) + protects buffer swap
    }

    // ---- epilogue: denom = self + other half-wave; O /= lsum; store bf16 ----
    float lrA = lra0 + lra1;
    float lrB = lrb0 + lrb1;
    lrA += __shfl_xor(lrA, 32);
    lrB += __shfl_xor(lrB, 32);
    float invA = 1.0f / lrA;   // for q = qw + l32
    float invB = 1.0f / lrB;   // for q = qw + 32 + l32
#pragma unroll
    for (int rr = 0; rr < 16; ++rr) {
        int rowq = (rr & 3) + 8 * (rr >> 2) + 4 * hi;  // C/D row -> q within subtile
        float ivA = __shfl(invA, rowq);
        float ivB = __shfl(invB, rowq);
        size_t baseA = (size_t)(b * S_ + qw + rowq) * D_ + h * DH_ + l32;
        ctx[baseA]      = f2b(OA0[rr] * ivA);
        ctx[baseA + 32] = f2b(OA1[rr] * ivA);
        size_t baseB = baseA + (size_t)32 * D_;
        ctx[baseB]      = f2b(OB0[rr] * ivB);
        ctx[baseB + 32] = f2b(OB1[rr] * ivB);
    }
}

// ---------- fused add3 + layernorm: LN(a + b + c) (split-K partial sum) ----------
__global__ __launch_bounds__(256) void add_ln3(const float* __restrict__ a,
                                               const float* __restrict__ b,
                                               const float* __restrict__ c,
                                               const float* __restrict__ g,
                                               const float* __restrict__ be,
                                               float* __restrict__ outF,
                                               u16* __restrict__ outB) {
    int row = blockIdx.x, tid = threadIdx.x;
    size_t base = (size_t)row * D_;
    float4 va = ((const float4*)(a + base))[tid];
    float4 vb = ((const float4*)(b + base))[tid];
    float4 vc = ((const float4*)(c + base))[tid];
    float x0 = va.x + vb.x + vc.x, x1 = va.y + vb.y + vc.y;
    float x2 = va.z + vb.z + vc.z, x3 = va.w + vb.w + vc.w;
    float s1 = x0 + x1 + x2 + x3;
    float s2 = x0 * x0 + x1 * x1 + x2 * x2 + x3 * x3;
#pragma unroll
    for (int off = 32; off; off >>= 1) {
        s1 += __shfl_xor(s1, off);
        s2 += __shfl_xor(s2, off);
    }
    __shared__ float r1[4], r2[4];
    int w = tid >> 6, lane = tid & 63;
    if (lane == 0) { r1[w] = s1; r2[w] = s2; }
    __syncthreads();
    s1 = r1[0] + r1[1] + r1[2] + r1[3];
    s2 = r2[0] + r2[1] + r2[2] + r2[3];
    float mean = s1 * (1.0f / D_);
    float var = s2 * (1.0f / D_) - mean * mean;
    float inv = rsqrtf(var + 1e-6f);
    float4 vg = ((const float4*)g)[tid];
    float4 vbe = ((const float4*)be)[tid];
    float o0 = (x0 - mean) * inv * vg.x + vbe.x;
    float o1 = (x1 - mean) * inv * vg.y + vbe.y;
    float o2 = (x2 - mean) * inv * vg.z + vbe.z;
    float o3 = (x3 - mean) * inv * vg.w + vbe.w;
    float4 o; o.x = o0; o.y = o1; o.z = o2; o.w = o3;
    ((float4*)(outF + base))[tid] = o;
    if (outB) {
        ushort4 u;
        u.x = f2b(o0); u.y = f2b(o1); u.z = f2b(o2); u.w = f2b(o3);
        ((ushort4*)(outB + base))[tid] = u;
    }
}

extern "C" void kernel_launch(void* const* d_in, const int* in_sizes, int n_in,
                              void* d_out, int out_size, void* d_ws, size_t ws_size,
                              hipStream_t stream) {
    const float* x   = (const float*)d_in[0];
    const float* wq  = (const float*)d_in[1];
    const float* bq  = (const float*)d_in[2];
    const float* wk  = (const float*)d_in[3];
    const float* bk  = (const float*)d_in[4];
    const float* wv  = (const float*)d_in[5];
    const float* bv  = (const float*)d_in[6];
    const float* wo  = (const float*)d_in[7];
    const float* bo  = (const float*)d_in[8];
    const float* w1  = (const float*)d_in[9];
    const float* b1  = (const float*)d_in[10];
    const float* w2  = (const float*)d_in[11];
    const float* b2  = (const float*)d_in[12];
    const float* g1  = (const float*)d_in[13];
    const float* be1 = (const float*)d_in[14];
    const float* g2  = (const float*)d_in[15];
    const float* be2 = (const float*)d_in[16];
    float* out = (float*)d_out;
    char* ws = (char*)d_ws;
    const size_t MB = 1u << 20;

    // layout (185 MB total, with aliasing):
    u16* xb      = (u16*)(ws + 0);        // 16 MB (dead after QKV gemm)
    u16* wqkvT   = (u16*)(ws + 16 * MB);  // 6 MB [wq^T*QSCALE | wk^T | wv^T]
    u16* woT     = (u16*)(ws + 22 * MB);  // 2 MB
    u16* w1T     = (u16*)(ws + 24 * MB);  // 8 MB
    u16* w2T     = (u16*)(ws + 32 * MB);  // 8 MB
    float* qkvb  = (float*)(ws + 40 * MB);// 12 KB
    u16* qkv     = (u16*)(ws + 41 * MB);  // 48 MB (dead after attn)
    u16* vtb     = (u16*)(ws + 89 * MB);  // 16 MB (dead after attn)
    u16* ctxb    = (u16*)(ws + 105 * MB); // 16 MB
    float* attn_out = (float*)(ws + 121 * MB); // 32 MB (dead after add_ln1)
    float* out1     = (float*)(ws + 153 * MB); // 32 MB
    u16* out1b   = (u16*)(ws + 0);        // 16 MB, aliases dead xb
    float* woP1  = (float*)(ws + 41 * MB); // 32 MB WO split-K partial 1 (qkv dead)
    u16* hidden  = (u16*)(ws + 41 * MB);  // 64 MB, aliases dead woP1/vtb after LN1
    float* ffn2p0 = (float*)(ws + 121 * MB); // split-K partial 0, aliases attn_out
    // FFN2 split-K partial 1 scratches in d_out (read then overwritten by add_ln3)

    // prep: cast + ALL weight transposes + bias concat in ONE launch
    prep<<<20492, 256, 0, stream>>>(x, xb, wq, wk, wv, wo, wqkvT, woT,
                                    w1, w1T, w2, w2T, bq, bk, bv, qkvb);

    // fused QKV projection: [8192,1024] @ [3072,1024]^T -> qkv [8192,3072]
    gemm256<<<dim3(12, 32, 1), 512, 0, stream>>>(xb, wqkvT, qkvb, nullptr, nullptr,
                                                 qkv, B_ * S_, QKVS, D_, D_, 0);
    transpose_v<<<dim3(S_ / 32, DH_ / 32, B_ * H_), dim3(32, 8), 0, stream>>>(qkv, vtb);

    // attention (flash-style, 64 q/wave, shared frag reads, KVBLK=128)
    attn_kernel<<<dim3(B_ * H_, S_ / 256), 256, 0, stream>>>(qkv, vtb, ctxb);

    // output projection, split-K=2 (grid 256 = full machine): z=0 -> attn_out
    // (+bo), z=1 -> woP1; residual + partial-sum + LN fused in add_ln3
    gemm256<<<dim3(4, 32, 2), 512, 0, stream>>>(ctxb, woT, bo, attn_out, woP1,
                                                nullptr, B_ * S_, D_, D_, D_ / 2, 0);
    add_ln3<<<B_ * S_, 256, 0, stream>>>(x, attn_out, woP1, g1, be1, out1, out1b);

    // FFN
    gemm256<<<dim3(16, 32, 1), 512, 0, stream>>>(out1b, w1T, b1, nullptr, nullptr,
                                                 hidden, B_ * S_, F_, D_, D_, 1);
    // FFN2 split-K=2: z=0 -> ffn2p0 (+b2), z=1 -> d_out (partial scratch)
    gemm256<<<dim3(4, 32, 2), 512, 0, stream>>>(hidden, w2T, b2, ffn2p0, out,
                                                nullptr, B_ * S_, D_, F_, F_ / 2, 0);
    add_ln3<<<B_ * S_, 256, 0, stream>>>(out1, ffn2p0, out, g2, be2, out, nullptr);
}

// Round 11
// 488.322 us; speedup vs baseline: 1.0197x; 1.0197x over previous
//
#include <hip/hip_runtime.h>

typedef unsigned short u16;
typedef unsigned int u32;

typedef __attribute__((ext_vector_type(8))) short short8;
typedef __attribute__((ext_vector_type(4))) float floatx4;
typedef __attribute__((ext_vector_type(16))) float floatx16;
typedef __attribute__((ext_vector_type(2))) unsigned int uint2v;
typedef __attribute__((ext_vector_type(4))) unsigned int uint4v;

// ---------- bf16 helpers ----------
static __device__ __forceinline__ u16 f2b(float f) {
    union { float f; u32 i; } v; v.f = f;
    u32 r = v.i + 0x7fffu + ((v.i >> 16) & 1u);
    return (u16)(r >> 16);
}
// 2^x via v_exp_f32
static __device__ __forceinline__ float exp2f_hw(float x) {
    return __builtin_amdgcn_exp2f(x);
}
// pack two f32 -> bf16x2 dword (RNE) in one instruction
static __device__ __forceinline__ u32 cvtpk(float lo, float hi) {
    u32 r;
    asm("v_cvt_pk_bf16_f32 %0, %1, %2" : "=v"(r) : "v"(lo), "v"(hi));
    return r;
}

static __device__ __forceinline__ floatx4 mfma16(short8 a, short8 b, floatx4 c) {
    return __builtin_amdgcn_mfma_f32_16x16x32_bf16(a, b, c, 0, 0, 0);
}
static __device__ __forceinline__ floatx16 mfma32(short8 a, short8 b, floatx16 c) {
    return __builtin_amdgcn_mfma_f32_32x32x16_bf16(a, b, c, 0, 0, 0);
}

// async global->LDS, 16B per lane; LDS dest must be wave-uniform base (HW adds lane*16)
typedef __attribute__((address_space(1))) const void gas_void;
typedef __attribute__((address_space(3))) void las_void;
static __device__ __forceinline__ void gl_lds16(const void* g, void* l) {
    __builtin_amdgcn_global_load_lds((gas_void*)g, (las_void*)l, 16, 0, 0);
}

// counted vmcnt wait (T4) + raw barrier, both with compiler memory fence
template<int N> static __device__ __forceinline__ void vmw() {
    if constexpr (N == 0)      asm volatile("s_waitcnt vmcnt(0)" ::: "memory");
    else if constexpr (N == 2) asm volatile("s_waitcnt vmcnt(2)" ::: "memory");
    else if constexpr (N == 4) asm volatile("s_waitcnt vmcnt(4)" ::: "memory");
}
#define SBAR() asm volatile("s_barrier" ::: "memory")

#define B_ 4
#define S_ 2048
#define D_ 1024
#define H_ 16
#define DH_ 64
#define F_ 4096
#define QKVS 3072   // row stride of fused qkv output

// (1/8) * log2(e), folded into wq/bq so logits come out in exp2 domain
#define QSCALE 0.18033688011112042f

// ---------- mega-prep: cast_b + 6 weight transposes + concat_bias, ONE launch ----
// grid = 8192 (cast x->xb) + 4096 (wq/wk/wv/wo T) + 4096 (w1 T) + 4096 (w2 T)
//      + 12 (bias concat) = 20492 blocks of 256. ~120 MB HBM traffic -> ~20us.
__global__ __launch_bounds__(256) void prep(
    const float* __restrict__ x, u16* __restrict__ xb,
    const float* __restrict__ wq, const float* __restrict__ wk,
    const float* __restrict__ wv, const float* __restrict__ wo,
    u16* __restrict__ wqkvT, u16* __restrict__ woT,
    const float* __restrict__ w1, u16* __restrict__ w1T,
    const float* __restrict__ w2, u16* __restrict__ w2T,
    const float* __restrict__ bq, const float* __restrict__ bk,
    const float* __restrict__ bv, float* __restrict__ qkvb) {
    int bid = blockIdx.x, tid = threadIdx.x;

    if (bid < 8192) {   // cast x (fp32) -> xb (bf16), 4 elems/thread, exact cover
        int id = bid * 256 + tid;
        float4 v = ((const float4*)x)[id];
        ushort4 u;
        u.x = f2b(v.x); u.y = f2b(v.y); u.z = f2b(v.z); u.w = f2b(v.w);
        ((ushort4*)xb)[id] = u;
        return;
    }
    bid -= 8192;

    if (bid >= 12288) { // concat + scale bias: [bq*QSCALE | bk | bv] (12 blocks)
        int i = (bid - 12288) * 256 + tid;
        float v;
        if (i < 1024) v = bq[i] * QSCALE;
        else if (i < 2048) v = bk[i - 1024];
        else v = bv[i - 2048];
        qkvb[i] = v;
        return;
    }

    // transpose+cast partitions (32x32 tile per block, 256 thr as 32x8)
    __shared__ float t[32][33];
    int x32 = tid & 31, y8 = tid >> 5;
    const float* in; u16* outp; float scale = 1.0f; int R, C, bx, by;
    if (bid < 4096) {          // four 1024x1024 weights
        int z = bid >> 10, rem = bid & 1023;
        bx = rem & 31; by = rem >> 5;
        in = (z == 0) ? wq : (z == 1) ? wk : (z == 2) ? wv : wo;
        outp = (z == 0) ? wqkvT : (z == 1) ? (wqkvT + 1024 * 1024)
             : (z == 2) ? (wqkvT + 2048 * 1024) : woT;
        scale = (z == 0) ? QSCALE : 1.0f;
        R = 1024; C = 1024;
    } else if (bid < 8192) {   // w1 [1024 x 4096]
        int rem = bid - 4096; bx = rem & 127; by = rem >> 7;
        in = w1; outp = w1T; R = 1024; C = 4096;
    } else {                   // w2 [4096 x 1024]
        int rem = bid - 8192; bx = rem & 31; by = rem >> 5;
        in = w2; outp = w2T; R = 4096; C = 1024;
    }
#pragma unroll
    for (int i = 0; i < 4; ++i) {
        int r = by * 32 + y8 + i * 8;
        t[y8 + i * 8][x32] = in[(size_t)r * C + bx * 32 + x32];
    }
    __syncthreads();
#pragma unroll
    for (int i = 0; i < 4; ++i) {
        int c = bx * 32 + y8 + i * 8;
        outp[(size_t)c * R + by * 32 + x32] = f2b(t[x32][y8 + i * 8] * scale);
    }
}

// ---------- transpose V: qkv[B*S, 3072] cols 2048.. -> vt [B,H,DH,S] bf16 ----------
__global__ void transpose_v(const u16* __restrict__ qkv, u16* __restrict__ vt) {
    __shared__ u16 t[32][33];
    int bh = blockIdx.z; int b = bh >> 4, h = bh & 15;
    int s0 = blockIdx.x * 32, d0 = blockIdx.y * 32;
    int x = threadIdx.x, y = threadIdx.y;  // 32x8
#pragma unroll
    for (int i = 0; i < 4; ++i)
        t[y + i * 8][x] =
            qkv[(size_t)(b * S_ + s0 + y + i * 8) * QKVS + 2048 + h * DH_ + d0 + x];
    __syncthreads();
#pragma unroll
    for (int i = 0; i < 4; ++i)
        vt[((size_t)bh * DH_ + d0 + y + i * 8) * S_ + s0 + x] = t[x][y + i * 8];
}

// ---------- gemm256 v4: 256x256 tile, 8-phase, slot-disciplined staging ----------
// (see round-7 comments: WAR-safe 3-5-phase prefetch distance, vmcnt(2) at
// ph4/ph8 only, one barrier per phase, XOR-swizzled 8KB chunks, split-K via z)
#define MFMA16X(MH)                                                        \
    __builtin_amdgcn_s_setprio(1);                                         \
    acc[(MH)*4+0][0] = mfma16(af0, bf0, acc[(MH)*4+0][0]);                 \
    acc[(MH)*4+0][1] = mfma16(af0, bf1, acc[(MH)*4+0][1]);                 \
    acc[(MH)*4+0][2] = mfma16(af0, bf2, acc[(MH)*4+0][2]);                 \
    acc[(MH)*4+0][3] = mfma16(af0, bf3, acc[(MH)*4+0][3]);                 \
    acc[(MH)*4+1][0] = mfma16(af1, bf0, acc[(MH)*4+1][0]);                 \
    acc[(MH)*4+1][1] = mfma16(af1, bf1, acc[(MH)*4+1][1]);                 \
    acc[(MH)*4+1][2] = mfma16(af1, bf2, acc[(MH)*4+1][2]);                 \
    acc[(MH)*4+1][3] = mfma16(af1, bf3, acc[(MH)*4+1][3]);                 \
    acc[(MH)*4+2][0] = mfma16(af2, bf0, acc[(MH)*4+2][0]);                 \
    acc[(MH)*4+2][1] = mfma16(af2, bf1, acc[(MH)*4+2][1]);                 \
    acc[(MH)*4+2][2] = mfma16(af2, bf2, acc[(MH)*4+2][2]);                 \
    acc[(MH)*4+2][3] = mfma16(af2, bf3, acc[(MH)*4+2][3]);                 \
    acc[(MH)*4+3][0] = mfma16(af3, bf0, acc[(MH)*4+3][0]);                 \
    acc[(MH)*4+3][1] = mfma16(af3, bf1, acc[(MH)*4+3][1]);                 \
    acc[(MH)*4+3][2] = mfma16(af3, bf2, acc[(MH)*4+3][2]);                 \
    acc[(MH)*4+3][3] = mfma16(af3, bf3, acc[(MH)*4+3][3]);                 \
    __builtin_amdgcn_s_setprio(0);

#define PPAIR(P, KH, STa, Wa, STb, Wb) {                                   \
    int ro = l * 64 + ((((KH) * 4 + quad) ^ l7) << 3);                     \
    const u16* bBp = &smem[32768 + (P) * 16384 + wc * 4096];               \
    short8 bf0 = *(const short8*)&bBp[ro];                                 \
    short8 bf1 = *(const short8*)&bBp[ro + 1024];                          \
    short8 bf2 = *(const short8*)&bBp[ro + 2048];                          \
    short8 bf3 = *(const short8*)&bBp[ro + 3072];                          \
    {   const u16* bAp = &smem[(P) * 16384 + (wr * 2 + 0) * 4096];         \
        short8 af0 = *(const short8*)&bAp[ro];                             \
        short8 af1 = *(const short8*)&bAp[ro + 1024];                      \
        short8 af2 = *(const short8*)&bAp[ro + 2048];                      \
        short8 af3 = *(const short8*)&bAp[ro + 3072];                      \
        STa; Wa;                                                           \
        MFMA16X(0)                                                         \
        SBAR();                                                            \
    }                                                                      \
    {   const u16* bAp = &smem[(P) * 16384 + (wr * 2 + 1) * 4096];         \
        short8 af0 = *(const short8*)&bAp[ro];                             \
        short8 af1 = *(const short8*)&bAp[ro + 1024];                      \
        short8 af2 = *(const short8*)&bAp[ro + 2048];                      \
        short8 af3 = *(const short8*)&bAp[ro + 3072];                      \
        STb; Wb;                                                           \
        MFMA16X(1)                                                         \
        SBAR();                                                            \
    } }

__global__ __launch_bounds__(512) void gemm256(const u16* __restrict__ A,
                                               const u16* __restrict__ Bt,
                                               const float* __restrict__ bias,
                                               float* __restrict__ outF,
                                               float* __restrict__ outF2,
                                               u16* __restrict__ outB,
                                               int M, int N, int K, int klen,
                                               int relu) {
    __shared__ __align__(16) u16 smem[65536];   // 128 KB

    int tid = threadIdx.x;
    int w = tid >> 6, lane = tid & 63, quad = lane >> 4, l = lane & 15;
    int wr = w >> 2, wc = w & 3;
    int l7 = l & 7;

    // XCD-aware bijective block swizzle (nwg % 8 == 0 for all our shapes)
    int nbN = gridDim.x, nwg = gridDim.x * gridDim.y;
    int flat = blockIdx.y * gridDim.x + blockIdx.x;
    int swz = (flat & 7) * (nwg >> 3) + (flat >> 3);
    int bM = swz / nbN, bN = swz % nbN;
    int koff = blockIdx.z * klen;

    floatx4 acc[8][4];
#pragma unroll
    for (int i = 0; i < 8; ++i)
#pragma unroll
        for (int j = 0; j < 4; ++j) acc[i][j] = (floatx4){0.f, 0.f, 0.f, 0.f};

    int rT = tid >> 3, cT = tid & 7;
    int cg8 = ((cT ^ (rT & 7)) << 3);
    const u16* gA0 = A + (size_t)(bM * 256 + rT) * K + koff + cg8;
    const u16* gB0 = Bt + (size_t)(bN * 256 + rT) * K + koff + cg8;

    auto stA = [&](int p, int ch, int t) {
        gl_lds16(gA0 + (size_t)(ch * 64) * K + t * 64,
                 (void*)&smem[p * 16384 + ch * 4096 + (w << 9)]);
    };
    auto stB = [&](int p, int hb, int t) {
        gl_lds16(gB0 + (size_t)(hb * 64) * K + t * 64,
                 (void*)&smem[32768 + p * 16384 + hb * 4096 + (w << 9)]);
    };

    // prologue: tile0 full -> P0, tile1 {A0,A2} -> P1; drain t0 (leave t1's 2)
    stA(0, 0, 0); stA(0, 1, 0); stA(0, 2, 0); stA(0, 3, 0);
    stB(0, 0, 0); stB(0, 1, 0); stB(0, 2, 0); stB(0, 3, 0);
    stA(1, 0, 1); stA(1, 2, 1);
    vmw<2>(); SBAR();

    const int NI = klen >> 7;   // iterations of 2 K-tiles
    for (int j = 0; j < NI - 1; ++j) {
        int to = 2 * j + 1, te = 2 * j + 2, tn = 2 * j + 3;
        PPAIR(0, 0, (stA(1,1,to), stA(1,3,to), stB(1,0,to), stB(1,1,to)), ((void)0),
                    (stB(1,2,to), stB(1,3,to)), ((void)0))
        PPAIR(0, 1, ((void)0), ((void)0),
                    (stA(0,0,te), stA(0,2,te)), vmw<2>())
        PPAIR(1, 0, (stA(0,1,te), stA(0,3,te), stB(0,0,te), stB(0,1,te)), ((void)0),
                    (stB(0,2,te), stB(0,3,te)), ((void)0))
        PPAIR(1, 1, ((void)0), ((void)0),
                    (stA(1,0,tn), stA(1,2,tn)), vmw<2>())
    }
    {   // final iteration: finish P1<-KT-1 at ph1/ph2, drain all at ph4
        int to = 2 * (NI - 1) + 1;
        PPAIR(0, 0, (stA(1,1,to), stA(1,3,to), stB(1,0,to), stB(1,1,to)), ((void)0),
                    (stB(1,2,to), stB(1,3,to)), ((void)0))
        PPAIR(0, 1, ((void)0), ((void)0), ((void)0), vmw<0>())
        PPAIR(1, 0, ((void)0), ((void)0), ((void)0), ((void)0))
        PPAIR(1, 1, ((void)0), ((void)0), ((void)0), ((void)0))
    }

    // epilogue: row-major store order (nt innermost); bias hoisted
    float* of = (blockIdx.z == 0) ? outF : outF2;
    const float* bp = (blockIdx.z == 0) ? bias : nullptr;
    float bv4[4];
#pragma unroll
    for (int nt = 0; nt < 4; ++nt) {
        int colg = bN * 256 + wc * 64 + nt * 16 + l;
        bv4[nt] = bp ? bp[colg] : 0.f;
    }
#pragma unroll
    for (int mt = 0; mt < 8; ++mt) {
#pragma unroll
        for (int rr = 0; rr < 4; ++rr) {
            int rowg = bM * 256 + wr * 128 + mt * 16 + quad * 4 + rr;
            size_t rb = (size_t)rowg * N + bN * 256 + wc * 64 + l;
#pragma unroll
            for (int nt = 0; nt < 4; ++nt) {
                float v = acc[mt][nt][rr] + bv4[nt];
                if (relu) v = fmaxf(v, 0.f);
                if (of) of[rb + nt * 16] = v;
                if (outB) outB[rb + nt * 16] = f2b(v);
            }
        }
    }
}

// ---------- flash attention v7 (KVBLK=64, the measured-best 80.6us config) ------
// r10 A/B: KVBLK=128 was a verified small regression (81.7us, WRITE_SIZE
// 16.4->24.1MB); revert to KVBLK=64. 64 q/wave shared-frag reads, swapped QK^T,
// in-register P (cvt_pk + permlane32_swap), K/V double-buffered via
// global_load_lds with XOR swizzle. Block = 4 waves x 64 q; grid (B*H, S/256).
#define PACK8(sv, rb, dst) {                                                   \
    u32 pa_ = cvtpk(sv[rb + 0], sv[rb + 1]), pb_ = cvtpk(sv[rb + 4], sv[rb + 5]); \
    u32 pc_ = cvtpk(sv[rb + 2], sv[rb + 3]), pd_ = cvtpk(sv[rb + 6], sv[rb + 7]); \
    uint2v t0_ = __builtin_amdgcn_permlane32_swap(pa_, pb_, 0, 0);             \
    uint2v t1_ = __builtin_amdgcn_permlane32_swap(pc_, pd_, 0, 0);             \
    union { uint4v u; short8 s8; } cv_;                                        \
    cv_.u = (uint4v){t0_[0], t1_[0], t0_[1], t1_[1]};                          \
    dst = cv_.s8; }

__global__ __launch_bounds__(256, 2) void attn_kernel(const u16* __restrict__ qkv,
                                                      const u16* __restrict__ vt,
                                                      u16* __restrict__ ctx) {
    __shared__ __align__(16) u16 Kb[2][64 * 64];   // 16 KB
    __shared__ __align__(16) u16 Vb[2][64 * 64];   // 16 KB

    int bh = blockIdx.x; int b = bh >> 4, h = bh & 15;
    int tid = threadIdx.x;
    int w = tid >> 6, lane = tid & 63;
    int l32 = lane & 31, hi = lane >> 5, row7 = lane & 7;
    int qw = blockIdx.y * 256 + w * 64;  // this wave's first q-row (64 rows/wave)

    int r = lane >> 3, c = lane & 7;
    int cs = ((c ^ r) << 3);
    const u16* gK0 = qkv + (size_t)(b * S_ + w * 16 + r) * QKVS + 1024 + h * DH_ + cs;
    const u16* gK1 = gK0 + (size_t)8 * QKVS;
    const u16* gV0 = vt + (size_t)(bh * DH_ + w * 16 + r) * S_ + cs;
    const u16* gV1 = gV0 + (size_t)8 * S_;

    auto stage = [&](int bb) {
        u16* lk = &Kb[bb][w * 16 * 64];
        u16* lv = &Vb[bb][w * 16 * 64];
        gl_lds16(gK0, lk);
        gl_lds16(gK1, lk + 8 * 64);
        gl_lds16(gV0, lv);
        gl_lds16(gV1, lv + 8 * 64);
        gK0 += (size_t)64 * QKVS; gK1 += (size_t)64 * QKVS;
        gV0 += 64; gV1 += 64;
    };

    // Q B-fragments for both subtiles: B[n = q][k = kc*16 + hi*8 + j]
    short8 qa0, qa1, qa2, qa3, qb0, qb1, qb2, qb3;
    {
        const u16* qpA = qkv + (size_t)(b * S_ + qw + l32) * QKVS + h * DH_ + hi * 8;
        qa0 = *(const short8*)(qpA);
        qa1 = *(const short8*)(qpA + 16);
        qa2 = *(const short8*)(qpA + 32);
        qa3 = *(const short8*)(qpA + 48);
        const u16* qpB = qpA + (size_t)32 * QKVS;
        qb0 = *(const short8*)(qpB);
        qb1 = *(const short8*)(qpB + 16);
        qb2 = *(const short8*)(qpB + 32);
        qb3 = *(const short8*)(qpB + 48);
    }

    floatx16 OA0, OA1, OB0, OB1;
#pragma unroll
    for (int i = 0; i < 16; ++i) { OA0[i] = 0.f; OA1[i] = 0.f; OB0[i] = 0.f; OB1[i] = 0.f; }
    float lra0 = 0.f, lra1 = 0.f, lrb0 = 0.f, lrb1 = 0.f;  // denominator partials

    int roff0 = l32 * 64;
    int roff1 = (32 + l32) * 64;

    stage(0);
    __syncthreads();

    const int NT = S_ / 64;
    for (int kt = 0; kt < NT; ++kt) {
        int cur = kt & 1;
        if (kt + 1 < NT) stage(cur ^ 1);

        const u16* Kc = Kb[cur];
        const u16* Vc = Vb[cur];

        short8 paA0, paA1, paA2, paA3, paB0, paB1, paB2, paB3;

        // ---- S^T tile 0 (keys 0..31): each K frag feeds both q-subtiles ----
        {
            floatx16 sA, sB;
#pragma unroll
            for (int i = 0; i < 16; ++i) { sA[i] = 0.f; sB[i] = 0.f; }
#pragma unroll
            for (int kc = 0; kc < 4; ++kc) {
                int ch = (((kc * 2 + hi) ^ row7) << 3);
                short8 ka = *(const short8*)&Kc[roff0 + ch];
                short8 qkA = (kc == 0) ? qa0 : (kc == 1) ? qa1 : (kc == 2) ? qa2 : qa3;
                short8 qkB = (kc == 0) ? qb0 : (kc == 1) ? qb1 : (kc == 2) ? qb2 : qb3;
                sA = mfma32(ka, qkA, sA);
                sB = mfma32(ka, qkB, sB);
            }
#pragma unroll
            for (int i = 0; i < 16; ++i) { sA[i] = exp2f_hw(sA[i]); sB[i] = exp2f_hw(sB[i]); }
#pragma unroll
            for (int i = 0; i < 16; i += 4) {
                lra0 += sA[i + 0] + sA[i + 1];
                lra1 += sA[i + 2] + sA[i + 3];
                lrb0 += sB[i + 0] + sB[i + 1];
                lrb1 += sB[i + 2] + sB[i + 3];
            }
            PACK8(sA, 0, paA0); PACK8(sA, 8, paA1);
            PACK8(sB, 0, paB0); PACK8(sB, 8, paB1);
        }

        // ---- S^T tile 1 (keys 32..63) ----
        {
            floatx16 sA, sB;
#pragma unroll
            for (int i = 0; i < 16; ++i) { sA[i] = 0.f; sB[i] = 0.f; }
#pragma unroll
            for (int kc = 0; kc < 4; ++kc) {
                int ch = (((kc * 2 + hi) ^ row7) << 3);
                short8 ka = *(const short8*)&Kc[roff1 + ch];
                short8 qkA = (kc == 0) ? qa0 : (kc == 1) ? qa1 : (kc == 2) ? qa2 : qa3;
                short8 qkB = (kc == 0) ? qb0 : (kc == 1) ? qb1 : (kc == 2) ? qb2 : qb3;
                sA = mfma32(ka, qkA, sA);
                sB = mfma32(ka, qkB, sB);
            }
#pragma unroll
            for (int i = 0; i < 16; ++i) { sA[i] = exp2f_hw(sA[i]); sB[i] = exp2f_hw(sB[i]); }
#pragma unroll
            for (int i = 0; i < 16; i += 4) {
                lra0 += sA[i + 0] + sA[i + 1];
                lra1 += sA[i + 2] + sA[i + 3];
                lrb0 += sB[i + 0] + sB[i + 1];
                lrb1 += sB[i + 2] + sB[i + 3];
            }
            PACK8(sA, 0, paA2); PACK8(sA, 8, paA3);
            PACK8(sB, 0, paB2); PACK8(sB, 8, paB3);
        }

        // ---- O += P @ V: each V frag feeds both q-subtiles ----
        {   // dh 0..31
            short8 vb0 = *(const short8*)&Vc[roff0 + (((0 + hi) ^ row7) << 3)];
            OA0 = mfma32(paA0, vb0, OA0);
            OB0 = mfma32(paB0, vb0, OB0);
            short8 vb1 = *(const short8*)&Vc[roff0 + (((2 + hi) ^ row7) << 3)];
            OA0 = mfma32(paA1, vb1, OA0);
            OB0 = mfma32(paB1, vb1, OB0);
            short8 vb2 = *(const short8*)&Vc[roff0 + (((4 + hi) ^ row7) << 3)];
            OA0 = mfma32(paA2, vb2, OA0);
            OB0 = mfma32(paB2, vb2, OB0);
            short8 vb3 = *(const short8*)&Vc[roff0 + (((6 + hi) ^ row7) << 3)];
            OA0 = mfma32(paA3, vb3, OA0);
            OB0 = mfma32(paB3, vb3, OB0);
        }
        {   // dh 32..63
            short8 vb0 = *(const short8*)&Vc[roff1 + (((0 + hi) ^ row7) << 3)];
            OA1 = mfma32(paA0, vb0, OA1);
            OB1 = mfma32(paB0, vb0, OB1);
            short8 vb1 = *(const short8*)&Vc[roff1 + (((2 + hi) ^ row7) << 3)];
            OA1 = mfma32(paA1, vb1, OA1);
            OB1 = mfma32(paB1, vb1, OB1);
            short8 vb2 = *(const short8*)&Vc[roff1 + (((4 + hi) ^ row7) << 3)];
            OA1 = mfma32(paA2, vb2, OA1);
            OB1 = mfma32(paB2, vb2, OB1);
            short8 vb3 = *(const short8*)&Vc[roff1 + (((6 + hi) ^ row7) << 3)];
            OA1 = mfma32(paA3, vb3, OA1);
            OB1 = mfma32(paB3, vb3, OB1);
        }

        __syncthreads();  // drains gl_lds (vmcnt) + protects buffer swap
    }

    // ---- epilogue: denom = self + other half-wave; O /= lsum; store bf16 ----
    float lrA = lra0 + lra1;
    float lrB = lrb0 + lrb1;
    lrA += __shfl_xor(lrA, 32);
    lrB += __shfl_xor(lrB, 32);
    float invA = 1.0f / lrA;   // for q = qw + l32
    float invB = 1.0f / lrB;   // for q = qw + 32 + l32
#pragma unroll
    for (int rr = 0; rr < 16; ++rr) {
        int rowq = (rr & 3) + 8 * (rr >> 2) + 4 * hi;  // C/D row -> q within subtile
        float ivA = __shfl(invA, rowq);
        float ivB = __shfl(invB, rowq);
        size_t baseA = (size_t)(b * S_ + qw + rowq) * D_ + h * DH_ + l32;
        ctx[baseA]      = f2b(OA0[rr] * ivA);
        ctx[baseA + 32] = f2b(OA1[rr] * ivA);
        size_t baseB = baseA + (size_t)32 * D_;
        ctx[baseB]      = f2b(OB0[rr] * ivB);
        ctx[baseB + 32] = f2b(OB1[rr] * ivB);
    }
}

// ---------- fused add3 + layernorm: LN(a + b + c) (split-K partial sum) ----------
__global__ __launch_bounds__(256) void add_ln3(const float* __restrict__ a,
                                               const float* __restrict__ b,
                                               const float* __restrict__ c,
                                               const float* __restrict__ g,
                                               const float* __restrict__ be,
                                               float* __restrict__ outF,
                                               u16* __restrict__ outB) {
    int row = blockIdx.x, tid = threadIdx.x;
    size_t base = (size_t)row * D_;
    float4 va = ((const float4*)(a + base))[tid];
    float4 vb = ((const float4*)(b + base))[tid];
    float4 vc = ((const float4*)(c + base))[tid];
    float x0 = va.x + vb.x + vc.x, x1 = va.y + vb.y + vc.y;
    float x2 = va.z + vb.z + vc.z, x3 = va.w + vb.w + vc.w;
    float s1 = x0 + x1 + x2 + x3;
    float s2 = x0 * x0 + x1 * x1 + x2 * x2 + x3 * x3;
#pragma unroll
    for (int off = 32; off; off >>= 1) {
        s1 += __shfl_xor(s1, off);
        s2 += __shfl_xor(s2, off);
    }
    __shared__ float r1[4], r2[4];
    int w = tid >> 6, lane = tid & 63;
    if (lane == 0) { r1[w] = s1; r2[w] = s2; }
    __syncthreads();
    s1 = r1[0] + r1[1] + r1[2] + r1[3];
    s2 = r2[0] + r2[1] + r2[2] + r2[3];
    float mean = s1 * (1.0f / D_);
    float var = s2 * (1.0f / D_) - mean * mean;
    float inv = rsqrtf(var + 1e-6f);
    float4 vg = ((const float4*)g)[tid];
    float4 vbe = ((const float4*)be)[tid];
    float o0 = (x0 - mean) * inv * vg.x + vbe.x;
    float o1 = (x1 - mean) * inv * vg.y + vbe.y;
    float o2 = (x2 - mean) * inv * vg.z + vbe.z;
    float o3 = (x3 - mean) * inv * vg.w + vbe.w;
    float4 o; o.x = o0; o.y = o1; o.z = o2; o.w = o3;
    ((float4*)(outF + base))[tid] = o;
    if (outB) {
        ushort4 u;
        u.x = f2b(o0); u.y = f2b(o1); u.z = f2b(o2); u.w = f2b(o3);
        ((ushort4*)(outB + base))[tid] = u;
    }
}

extern "C" void kernel_launch(void* const* d_in, const int* in_sizes, int n_in,
                              void* d_out, int out_size, void* d_ws, size_t ws_size,
                              hipStream_t stream) {
    const float* x   = (const float*)d_in[0];
    const float* wq  = (const float*)d_in[1];
    const float* bq  = (const float*)d_in[2];
    const float* wk  = (const float*)d_in[3];
    const float* bk  = (const float*)d_in[4];
    const float* wv  = (const float*)d_in[5];
    const float* bv  = (const float*)d_in[6];
    const float* wo  = (const float*)d_in[7];
    const float* bo  = (const float*)d_in[8];
    const float* w1  = (const float*)d_in[9];
    const float* b1  = (const float*)d_in[10];
    const float* w2  = (const float*)d_in[11];
    const float* b2  = (const float*)d_in[12];
    const float* g1  = (const float*)d_in[13];
    const float* be1 = (const float*)d_in[14];
    const float* g2  = (const float*)d_in[15];
    const float* be2 = (const float*)d_in[16];
    float* out = (float*)d_out;
    char* ws = (char*)d_ws;
    const size_t MB = 1u << 20;

    // layout (185 MB total, with aliasing):
    u16* xb      = (u16*)(ws + 0);        // 16 MB (dead after QKV gemm)
    u16* wqkvT   = (u16*)(ws + 16 * MB);  // 6 MB [wq^T*QSCALE | wk^T | wv^T]
    u16* woT     = (u16*)(ws + 22 * MB);  // 2 MB
    u16* w1T     = (u16*)(ws + 24 * MB);  // 8 MB
    u16* w2T     = (u16*)(ws + 32 * MB);  // 8 MB
    float* qkvb  = (float*)(ws + 40 * MB);// 12 KB
    u16* qkv     = (u16*)(ws + 41 * MB);  // 48 MB (dead after attn)
    u16* vtb     = (u16*)(ws + 89 * MB);  // 16 MB (dead after attn)
    u16* ctxb    = (u16*)(ws + 105 * MB); // 16 MB
    float* attn_out = (float*)(ws + 121 * MB); // 32 MB (dead after add_ln1)
    float* out1     = (float*)(ws + 153 * MB); // 32 MB
    u16* out1b   = (u16*)(ws + 0);        // 16 MB, aliases dead xb
    float* woP1  = (float*)(ws + 41 * MB); // 32 MB WO split-K partial 1 (qkv dead)
    u16* hidden  = (u16*)(ws + 41 * MB);  // 64 MB, aliases dead woP1/vtb after LN1
    float* ffn2p0 = (float*)(ws + 121 * MB); // split-K partial 0, aliases attn_out
    // FFN2 split-K partial 1 scratches in d_out (read then overwritten by add_ln3)

    // prep: cast + ALL weight transposes + bias concat in ONE launch
    prep<<<20492, 256, 0, stream>>>(x, xb, wq, wk, wv, wo, wqkvT, woT,
                                    w1, w1T, w2, w2T, bq, bk, bv, qkvb);

    // fused QKV projection: [8192,1024] @ [3072,1024]^T -> qkv [8192,3072]
    gemm256<<<dim3(12, 32, 1), 512, 0, stream>>>(xb, wqkvT, qkvb, nullptr, nullptr,
                                                 qkv, B_ * S_, QKVS, D_, D_, 0);
    transpose_v<<<dim3(S_ / 32, DH_ / 32, B_ * H_), dim3(32, 8), 0, stream>>>(qkv, vtb);

    // attention (flash-style, 64 q/wave, shared frag reads, KVBLK=64)
    attn_kernel<<<dim3(B_ * H_, S_ / 256), 256, 0, stream>>>(qkv, vtb, ctxb);

    // output projection, split-K=2 (grid 256 = full machine): z=0 -> attn_out
    // (+bo), z=1 -> woP1; residual + partial-sum + LN fused in add_ln3
    gemm256<<<dim3(4, 32, 2), 512, 0, stream>>>(ctxb, woT, bo, attn_out, woP1,
                                                nullptr, B_ * S_, D_, D_, D_ / 2, 0);
    add_ln3<<<B_ * S_, 256, 0, stream>>>(x, attn_out, woP1, g1, be1, out1, out1b);

    // FFN
    gemm256<<<dim3(16, 32, 1), 512, 0, stream>>>(out1b, w1T, b1, nullptr, nullptr,
                                                 hidden, B_ * S_, F_, D_, D_, 1);
    // FFN2 split-K=2: z=0 -> ffn2p0 (+b2), z=1 -> d_out (partial scratch)
    gemm256<<<dim3(4, 32, 2), 512, 0, stream>>>(hidden, w2T, b2, ffn2p0, out,
                                                nullptr, B_ * S_, D_, F_, F_ / 2, 0);
    add_ln3<<<B_ * S_, 256, 0, stream>>>(out1, ffn2p0, out, g2, be2, out, nullptr);
}

// Round 12
// 478.474 us; speedup vs baseline: 1.0407x; 1.0206x over previous
//
#include <hip/hip_runtime.h>

typedef unsigned short u16;
typedef unsigned int u32;

typedef __attribute__((ext_vector_type(8))) short short8;
typedef __attribute__((ext_vector_type(4))) float floatx4;
typedef __attribute__((ext_vector_type(16))) float floatx16;
typedef __attribute__((ext_vector_type(2))) unsigned int uint2v;
typedef __attribute__((ext_vector_type(4))) unsigned int uint4v;

// ---------- bf16 helpers ----------
static __device__ __forceinline__ u16 f2b(float f) {
    union { float f; u32 i; } v; v.f = f;
    u32 r = v.i + 0x7fffu + ((v.i >> 16) & 1u);
    return (u16)(r >> 16);
}
// 2^x via v_exp_f32
static __device__ __forceinline__ float exp2f_hw(float x) {
    return __builtin_amdgcn_exp2f(x);
}
// pack two f32 -> bf16x2 dword (RNE) in one instruction
static __device__ __forceinline__ u32 cvtpk(float lo, float hi) {
    u32 r;
    asm("v_cvt_pk_bf16_f32 %0, %1, %2" : "=v"(r) : "v"(lo), "v"(hi));
    return r;
}

static __device__ __forceinline__ floatx4 mfma16(short8 a, short8 b, floatx4 c) {
    return __builtin_amdgcn_mfma_f32_16x16x32_bf16(a, b, c, 0, 0, 0);
}
static __device__ __forceinline__ floatx16 mfma32(short8 a, short8 b, floatx16 c) {
    return __builtin_amdgcn_mfma_f32_32x32x16_bf16(a, b, c, 0, 0, 0);
}

// async global->LDS, 16B per lane; LDS dest must be wave-uniform base (HW adds lane*16)
typedef __attribute__((address_space(1))) const void gas_void;
typedef __attribute__((address_space(3))) void las_void;
static __device__ __forceinline__ void gl_lds16(const void* g, void* l) {
    __builtin_amdgcn_global_load_lds((gas_void*)g, (las_void*)l, 16, 0, 0);
}

// counted vmcnt wait (T4) + raw barrier, both with compiler memory fence
template<int N> static __device__ __forceinline__ void vmw() {
    if constexpr (N == 0)      asm volatile("s_waitcnt vmcnt(0)" ::: "memory");
    else if constexpr (N == 2) asm volatile("s_waitcnt vmcnt(2)" ::: "memory");
    else if constexpr (N == 4) asm volatile("s_waitcnt vmcnt(4)" ::: "memory");
}
#define SBAR() asm volatile("s_barrier" ::: "memory")

#define B_ 4
#define S_ 2048
#define D_ 1024
#define H_ 16
#define DH_ 64
#define F_ 4096
#define QKVS 3072   // row stride of fused qkv output

// (1/8) * log2(e), folded into wq/bq so logits come out in exp2 domain
#define QSCALE 0.18033688011112042f

// ---------- mega-prep: cast_b + 6 weight transposes + concat_bias, ONE launch ----
__global__ __launch_bounds__(256) void prep(
    const float* __restrict__ x, u16* __restrict__ xb,
    const float* __restrict__ wq, const float* __restrict__ wk,
    const float* __restrict__ wv, const float* __restrict__ wo,
    u16* __restrict__ wqkvT, u16* __restrict__ woT,
    const float* __restrict__ w1, u16* __restrict__ w1T,
    const float* __restrict__ w2, u16* __restrict__ w2T,
    const float* __restrict__ bq, const float* __restrict__ bk,
    const float* __restrict__ bv, float* __restrict__ qkvb) {
    int bid = blockIdx.x, tid = threadIdx.x;

    if (bid < 8192) {   // cast x (fp32) -> xb (bf16), 4 elems/thread, exact cover
        int id = bid * 256 + tid;
        float4 v = ((const float4*)x)[id];
        ushort4 u;
        u.x = f2b(v.x); u.y = f2b(v.y); u.z = f2b(v.z); u.w = f2b(v.w);
        ((ushort4*)xb)[id] = u;
        return;
    }
    bid -= 8192;

    if (bid >= 12288) { // concat + scale bias: [bq*QSCALE | bk | bv] (12 blocks)
        int i = (bid - 12288) * 256 + tid;
        float v;
        if (i < 1024) v = bq[i] * QSCALE;
        else if (i < 2048) v = bk[i - 1024];
        else v = bv[i - 2048];
        qkvb[i] = v;
        return;
    }

    // transpose+cast partitions (32x32 tile per block, 256 thr as 32x8)
    __shared__ float t[32][33];
    int x32 = tid & 31, y8 = tid >> 5;
    const float* in; u16* outp; float scale = 1.0f; int R, C, bx, by;
    if (bid < 4096) {          // four 1024x1024 weights
        int z = bid >> 10, rem = bid & 1023;
        bx = rem & 31; by = rem >> 5;
        in = (z == 0) ? wq : (z == 1) ? wk : (z == 2) ? wv : wo;
        outp = (z == 0) ? wqkvT : (z == 1) ? (wqkvT + 1024 * 1024)
             : (z == 2) ? (wqkvT + 2048 * 1024) : woT;
        scale = (z == 0) ? QSCALE : 1.0f;
        R = 1024; C = 1024;
    } else if (bid < 8192) {   // w1 [1024 x 4096]
        int rem = bid - 4096; bx = rem & 127; by = rem >> 7;
        in = w1; outp = w1T; R = 1024; C = 4096;
    } else {                   // w2 [4096 x 1024]
        int rem = bid - 8192; bx = rem & 31; by = rem >> 5;
        in = w2; outp = w2T; R = 4096; C = 1024;
    }
#pragma unroll
    for (int i = 0; i < 4; ++i) {
        int r = by * 32 + y8 + i * 8;
        t[y8 + i * 8][x32] = in[(size_t)r * C + bx * 32 + x32];
    }
    __syncthreads();
#pragma unroll
    for (int i = 0; i < 4; ++i) {
        int c = bx * 32 + y8 + i * 8;
        outp[(size_t)c * R + by * 32 + x32] = f2b(t[x32][y8 + i * 8] * scale);
    }
}

// ---------- transpose V: qkv[B*S, 3072] cols 2048.. -> vt [B,H,DH,S] bf16 ----------
__global__ void transpose_v(const u16* __restrict__ qkv, u16* __restrict__ vt) {
    __shared__ u16 t[32][33];
    int bh = blockIdx.z; int b = bh >> 4, h = bh & 15;
    int s0 = blockIdx.x * 32, d0 = blockIdx.y * 32;
    int x = threadIdx.x, y = threadIdx.y;  // 32x8
#pragma unroll
    for (int i = 0; i < 4; ++i)
        t[y + i * 8][x] =
            qkv[(size_t)(b * S_ + s0 + y + i * 8) * QKVS + 2048 + h * DH_ + d0 + x];
    __syncthreads();
#pragma unroll
    for (int i = 0; i < 4; ++i)
        vt[((size_t)bh * DH_ + d0 + y + i * 8) * S_ + s0 + x] = t[x][y + i * 8];
}

// ---------- gemm256 v4: 256x256 tile, 8-phase, slot-disciplined staging ----------
// (see round-7 comments: WAR-safe 3-5-phase prefetch distance, vmcnt(2) at
// ph4/ph8 only, one barrier per phase, XOR-swizzled 8KB chunks)
#define MFMA16X(MH)                                                        \
    __builtin_amdgcn_s_setprio(1);                                         \
    acc[(MH)*4+0][0] = mfma16(af0, bf0, acc[(MH)*4+0][0]);                 \
    acc[(MH)*4+0][1] = mfma16(af0, bf1, acc[(MH)*4+0][1]);                 \
    acc[(MH)*4+0][2] = mfma16(af0, bf2, acc[(MH)*4+0][2]);                 \
    acc[(MH)*4+0][3] = mfma16(af0, bf3, acc[(MH)*4+0][3]);                 \
    acc[(MH)*4+1][0] = mfma16(af1, bf0, acc[(MH)*4+1][0]);                 \
    acc[(MH)*4+1][1] = mfma16(af1, bf1, acc[(MH)*4+1][1]);                 \
    acc[(MH)*4+1][2] = mfma16(af1, bf2, acc[(MH)*4+1][2]);                 \
    acc[(MH)*4+1][3] = mfma16(af1, bf3, acc[(MH)*4+1][3]);                 \
    acc[(MH)*4+2][0] = mfma16(af2, bf0, acc[(MH)*4+2][0]);                 \
    acc[(MH)*4+2][1] = mfma16(af2, bf1, acc[(MH)*4+2][1]);                 \
    acc[(MH)*4+2][2] = mfma16(af2, bf2, acc[(MH)*4+2][2]);                 \
    acc[(MH)*4+2][3] = mfma16(af2, bf3, acc[(MH)*4+2][3]);                 \
    acc[(MH)*4+3][0] = mfma16(af3, bf0, acc[(MH)*4+3][0]);                 \
    acc[(MH)*4+3][1] = mfma16(af3, bf1, acc[(MH)*4+3][1]);                 \
    acc[(MH)*4+3][2] = mfma16(af3, bf2, acc[(MH)*4+3][2]);                 \
    acc[(MH)*4+3][3] = mfma16(af3, bf3, acc[(MH)*4+3][3]);                 \
    __builtin_amdgcn_s_setprio(0);

#define PPAIR(P, KH, STa, Wa, STb, Wb) {                                   \
    int ro = l * 64 + ((((KH) * 4 + quad) ^ l7) << 3);                     \
    const u16* bBp = &smem[32768 + (P) * 16384 + wc * 4096];               \
    short8 bf0 = *(const short8*)&bBp[ro];                                 \
    short8 bf1 = *(const short8*)&bBp[ro + 1024];                          \
    short8 bf2 = *(const short8*)&bBp[ro + 2048];                          \
    short8 bf3 = *(const short8*)&bBp[ro + 3072];                          \
    {   const u16* bAp = &smem[(P) * 16384 + (wr * 2 + 0) * 4096];         \
        short8 af0 = *(const short8*)&bAp[ro];                             \
        short8 af1 = *(const short8*)&bAp[ro + 1024];                      \
        short8 af2 = *(const short8*)&bAp[ro + 2048];                      \
        short8 af3 = *(const short8*)&bAp[ro + 3072];                      \
        STa; Wa;                                                           \
        MFMA16X(0)                                                         \
        SBAR();                                                            \
    }                                                                      \
    {   const u16* bAp = &smem[(P) * 16384 + (wr * 2 + 1) * 4096];         \
        short8 af0 = *(const short8*)&bAp[ro];                             \
        short8 af1 = *(const short8*)&bAp[ro + 1024];                      \
        short8 af2 = *(const short8*)&bAp[ro + 2048];                      \
        short8 af3 = *(const short8*)&bAp[ro + 3072];                      \
        STb; Wb;                                                           \
        MFMA16X(1)                                                         \
        SBAR();                                                            \
    } }

__global__ __launch_bounds__(512) void gemm256(const u16* __restrict__ A,
                                               const u16* __restrict__ Bt,
                                               const float* __restrict__ bias,
                                               float* __restrict__ outF,
                                               u16* __restrict__ outB,
                                               int M, int N, int K, int relu) {
    __shared__ __align__(16) u16 smem[65536];   // 128 KB

    int tid = threadIdx.x;
    int w = tid >> 6, lane = tid & 63, quad = lane >> 4, l = lane & 15;
    int wr = w >> 2, wc = w & 3;
    int l7 = l & 7;

    // XCD-aware bijective block swizzle (nwg % 8 == 0 for all our shapes)
    int nbN = gridDim.x, nwg = gridDim.x * gridDim.y;
    int flat = blockIdx.y * gridDim.x + blockIdx.x;
    int swz = (flat & 7) * (nwg >> 3) + (flat >> 3);
    int bM = swz / nbN, bN = swz % nbN;

    floatx4 acc[8][4];
#pragma unroll
    for (int i = 0; i < 8; ++i)
#pragma unroll
        for (int j = 0; j < 4; ++j) acc[i][j] = (floatx4){0.f, 0.f, 0.f, 0.f};

    int rT = tid >> 3, cT = tid & 7;
    int cg8 = ((cT ^ (rT & 7)) << 3);
    const u16* gA0 = A + (size_t)(bM * 256 + rT) * K + cg8;
    const u16* gB0 = Bt + (size_t)(bN * 256 + rT) * K + cg8;

    auto stA = [&](int p, int ch, int t) {
        gl_lds16(gA0 + (size_t)(ch * 64) * K + t * 64,
                 (void*)&smem[p * 16384 + ch * 4096 + (w << 9)]);
    };
    auto stB = [&](int p, int hb, int t) {
        gl_lds16(gB0 + (size_t)(hb * 64) * K + t * 64,
                 (void*)&smem[32768 + p * 16384 + hb * 4096 + (w << 9)]);
    };

    // prologue: tile0 full -> P0, tile1 {A0,A2} -> P1; drain t0 (leave t1's 2)
    stA(0, 0, 0); stA(0, 1, 0); stA(0, 2, 0); stA(0, 3, 0);
    stB(0, 0, 0); stB(0, 1, 0); stB(0, 2, 0); stB(0, 3, 0);
    stA(1, 0, 1); stA(1, 2, 1);
    vmw<2>(); SBAR();

    const int NI = K >> 7;   // iterations of 2 K-tiles
    for (int j = 0; j < NI - 1; ++j) {
        int to = 2 * j + 1, te = 2 * j + 2, tn = 2 * j + 3;
        PPAIR(0, 0, (stA(1,1,to), stA(1,3,to), stB(1,0,to), stB(1,1,to)), ((void)0),
                    (stB(1,2,to), stB(1,3,to)), ((void)0))
        PPAIR(0, 1, ((void)0), ((void)0),
                    (stA(0,0,te), stA(0,2,te)), vmw<2>())
        PPAIR(1, 0, (stA(0,1,te), stA(0,3,te), stB(0,0,te), stB(0,1,te)), ((void)0),
                    (stB(0,2,te), stB(0,3,te)), ((void)0))
        PPAIR(1, 1, ((void)0), ((void)0),
                    (stA(1,0,tn), stA(1,2,tn)), vmw<2>())
    }
    {   // final iteration: finish P1<-KT-1 at ph1/ph2, drain all at ph4
        int to = 2 * (NI - 1) + 1;
        PPAIR(0, 0, (stA(1,1,to), stA(1,3,to), stB(1,0,to), stB(1,1,to)), ((void)0),
                    (stB(1,2,to), stB(1,3,to)), ((void)0))
        PPAIR(0, 1, ((void)0), ((void)0), ((void)0), vmw<0>())
        PPAIR(1, 0, ((void)0), ((void)0), ((void)0), ((void)0))
        PPAIR(1, 1, ((void)0), ((void)0), ((void)0), ((void)0))
    }

    // epilogue: row-major store order (nt innermost); bias hoisted
    float bv4[4];
#pragma unroll
    for (int nt = 0; nt < 4; ++nt) {
        int colg = bN * 256 + wc * 64 + nt * 16 + l;
        bv4[nt] = bias ? bias[colg] : 0.f;
    }
#pragma unroll
    for (int mt = 0; mt < 8; ++mt) {
#pragma unroll
        for (int rr = 0; rr < 4; ++rr) {
            int rowg = bM * 256 + wr * 128 + mt * 16 + quad * 4 + rr;
            size_t rb = (size_t)rowg * N + bN * 256 + wc * 64 + l;
#pragma unroll
            for (int nt = 0; nt < 4; ++nt) {
                float v = acc[mt][nt][rr] + bv4[nt];
                if (relu) v = fmaxf(v, 0.f);
                if (outF) outF[rb + nt * 16] = v;
                if (outB) outB[rb + nt * 16] = f2b(v);
            }
        }
    }
}

// ---------- gemm256b: 256x128 tile for N=1024 gemms (full machine, NO split-K) --
// Subset of the proven v4 schedule: A-side identical (4x 8KB chunks, same frag
// reads, same MH phases); B shrinks to 2 chunks/K-tile (128 rows). 8 waves as
// 2M x 4N of (128 x 32) outputs; acc[8][2]. LDS 96 KB. Slot-discipline FIFO
// re-derived for 6-chunk tiles: prologue {t0 full(6) + t1{A0,A2}}, vmw<2>;
// per iter stage {A1,A3,B0,B1}@ph1, {A0,A2}@ph4+vmw<2>, {A1,A3,B0,B1}@ph5,
// {A0,A2}@ph8+vmw<2>. WAR: A0/A2 last read ph3 (staged ph4), A1/A3 ph4 (ph5),
// B ph4 (ph1 of next P-half after barrier). Waits drain exactly the 6 chunks
// of the tile read next. Replaces split-K for WO/FFN2: grid (8,32) = 256
// blocks = full machine, no 64MB fp32 partial round-trip.
#define MFMA8X(MH)                                                         \
    __builtin_amdgcn_s_setprio(1);                                         \
    acc[(MH)*4+0][0] = mfma16(af0, bf0, acc[(MH)*4+0][0]);                 \
    acc[(MH)*4+0][1] = mfma16(af0, bf1, acc[(MH)*4+0][1]);                 \
    acc[(MH)*4+1][0] = mfma16(af1, bf0, acc[(MH)*4+1][0]);                 \
    acc[(MH)*4+1][1] = mfma16(af1, bf1, acc[(MH)*4+1][1]);                 \
    acc[(MH)*4+2][0] = mfma16(af2, bf0, acc[(MH)*4+2][0]);                 \
    acc[(MH)*4+2][1] = mfma16(af2, bf1, acc[(MH)*4+2][1]);                 \
    acc[(MH)*4+3][0] = mfma16(af3, bf0, acc[(MH)*4+3][0]);                 \
    acc[(MH)*4+3][1] = mfma16(af3, bf1, acc[(MH)*4+3][1]);                 \
    __builtin_amdgcn_s_setprio(0);

#define PPAIRB(P, KH, STa, Wa, STb, Wb) {                                  \
    int sw = (((KH) * 4 + quad) ^ l7) << 3;                                \
    int ro = l * 64 + sw;                                                  \
    int rob = ((wc & 1) * 32 + l) * 64 + sw;                               \
    const u16* bBp = &smem[32768 + (P) * 8192 + (wc >> 1) * 4096];         \
    short8 bf0 = *(const short8*)&bBp[rob];                                \
    short8 bf1 = *(const short8*)&bBp[rob + 1024];                         \
    {   const u16* bAp = &smem[(P) * 16384 + (wr * 2 + 0) * 4096];         \
        short8 af0 = *(const short8*)&bAp[ro];                             \
        short8 af1 = *(const short8*)&bAp[ro + 1024];                      \
        short8 af2 = *(const short8*)&bAp[ro + 2048];                      \
        short8 af3 = *(const short8*)&bAp[ro + 3072];                      \
        STa; Wa;                                                           \
        MFMA8X(0)                                                          \
        SBAR();                                                            \
    }                                                                      \
    {   const u16* bAp = &smem[(P) * 16384 + (wr * 2 + 1) * 4096];         \
        short8 af0 = *(const short8*)&bAp[ro];                             \
        short8 af1 = *(const short8*)&bAp[ro + 1024];                      \
        short8 af2 = *(const short8*)&bAp[ro + 2048];                      \
        short8 af3 = *(const short8*)&bAp[ro + 3072];                      \
        STb; Wb;                                                           \
        MFMA8X(1)                                                          \
        SBAR();                                                            \
    } }

__global__ __launch_bounds__(512) void gemm256b(const u16* __restrict__ A,
                                                const u16* __restrict__ Bt,
                                                const float* __restrict__ bias,
                                                float* __restrict__ outF,
                                                u16* __restrict__ outB,
                                                int M, int N, int K, int relu) {
    __shared__ __align__(16) u16 smem[49152];   // 96 KB: A 64KB + B 32KB

    int tid = threadIdx.x;
    int w = tid >> 6, lane = tid & 63, quad = lane >> 4, l = lane & 15;
    int wr = w >> 2, wc = w & 3;
    int l7 = l & 7;

    // XCD-aware bijective block swizzle (nwg = 256, divisible by 8)
    int nbN = gridDim.x, nwg = gridDim.x * gridDim.y;
    int flat = blockIdx.y * gridDim.x + blockIdx.x;
    int swz = (flat & 7) * (nwg >> 3) + (flat >> 3);
    int bM = swz / nbN, bN = swz % nbN;

    floatx4 acc[8][2];
#pragma unroll
    for (int i = 0; i < 8; ++i)
#pragma unroll
        for (int j = 0; j < 2; ++j) acc[i][j] = (floatx4){0.f, 0.f, 0.f, 0.f};

    int rT = tid >> 3, cT = tid & 7;
    int cg8 = ((cT ^ (rT & 7)) << 3);
    const u16* gA0 = A + (size_t)(bM * 256 + rT) * K + cg8;
    const u16* gB0 = Bt + (size_t)(bN * 128 + rT) * K + cg8;

    auto stA = [&](int p, int ch, int t) {
        gl_lds16(gA0 + (size_t)(ch * 64) * K + t * 64,
                 (void*)&smem[p * 16384 + ch * 4096 + (w << 9)]);
    };
    auto stB = [&](int p, int hb, int t) {
        gl_lds16(gB0 + (size_t)(hb * 64) * K + t * 64,
                 (void*)&smem[32768 + p * 8192 + hb * 4096 + (w << 9)]);
    };

    // prologue: tile0 (6 chunks) -> P0, tile1 {A0,A2} -> P1; drain t0
    stA(0, 0, 0); stA(0, 1, 0); stA(0, 2, 0); stA(0, 3, 0);
    stB(0, 0, 0); stB(0, 1, 0);
    stA(1, 0, 1); stA(1, 2, 1);
    vmw<2>(); SBAR();

    const int NI = K >> 7;   // iterations of 2 K-tiles
    for (int j = 0; j < NI - 1; ++j) {
        int to = 2 * j + 1, te = 2 * j + 2, tn = 2 * j + 3;
        PPAIRB(0, 0, (stA(1,1,to), stA(1,3,to), stB(1,0,to), stB(1,1,to)), ((void)0),
                     ((void)0), ((void)0))
        PPAIRB(0, 1, ((void)0), ((void)0),
                     (stA(0,0,te), stA(0,2,te)), vmw<2>())
        PPAIRB(1, 0, (stA(0,1,te), stA(0,3,te), stB(0,0,te), stB(0,1,te)), ((void)0),
                     ((void)0), ((void)0))
        PPAIRB(1, 1, ((void)0), ((void)0),
                     (stA(1,0,tn), stA(1,2,tn)), vmw<2>())
    }
    {   // final iteration: finish P1<-KT-1 at ph1, drain all at ph4
        int to = 2 * (NI - 1) + 1;
        PPAIRB(0, 0, (stA(1,1,to), stA(1,3,to), stB(1,0,to), stB(1,1,to)), ((void)0),
                     ((void)0), ((void)0))
        PPAIRB(0, 1, ((void)0), ((void)0), ((void)0), vmw<0>())
        PPAIRB(1, 0, ((void)0), ((void)0), ((void)0), ((void)0))
        PPAIRB(1, 1, ((void)0), ((void)0), ((void)0), ((void)0))
    }

    // epilogue: row-major store order (nt innermost); bias hoisted
    float bv2[2];
#pragma unroll
    for (int nt = 0; nt < 2; ++nt) {
        int colg = bN * 128 + wc * 32 + nt * 16 + l;
        bv2[nt] = bias ? bias[colg] : 0.f;
    }
#pragma unroll
    for (int mt = 0; mt < 8; ++mt) {
#pragma unroll
        for (int rr = 0; rr < 4; ++rr) {
            int rowg = bM * 256 + wr * 128 + mt * 16 + quad * 4 + rr;
            size_t rb = (size_t)rowg * N + bN * 128 + wc * 32 + l;
#pragma unroll
            for (int nt = 0; nt < 2; ++nt) {
                float v = acc[mt][nt][rr] + bv2[nt];
                if (relu) v = fmaxf(v, 0.f);
                if (outF) outF[rb + nt * 16] = v;
                if (outB) outB[rb + nt * 16] = f2b(v);
            }
        }
    }
}

// ---------- flash attention v7 (KVBLK=64, measured-best 78us config) ------------
#define PACK8(sv, rb, dst) {                                                   \
    u32 pa_ = cvtpk(sv[rb + 0], sv[rb + 1]), pb_ = cvtpk(sv[rb + 4], sv[rb + 5]); \
    u32 pc_ = cvtpk(sv[rb + 2], sv[rb + 3]), pd_ = cvtpk(sv[rb + 6], sv[rb + 7]); \
    uint2v t0_ = __builtin_amdgcn_permlane32_swap(pa_, pb_, 0, 0);             \
    uint2v t1_ = __builtin_amdgcn_permlane32_swap(pc_, pd_, 0, 0);             \
    union { uint4v u; short8 s8; } cv_;                                        \
    cv_.u = (uint4v){t0_[0], t1_[0], t0_[1], t1_[1]};                          \
    dst = cv_.s8; }

__global__ __launch_bounds__(256, 2) void attn_kernel(const u16* __restrict__ qkv,
                                                      const u16* __restrict__ vt,
                                                      u16* __restrict__ ctx) {
    __shared__ __align__(16) u16 Kb[2][64 * 64];   // 16 KB
    __shared__ __align__(16) u16 Vb[2][64 * 64];   // 16 KB

    int bh = blockIdx.x; int b = bh >> 4, h = bh & 15;
    int tid = threadIdx.x;
    int w = tid >> 6, lane = tid & 63;
    int l32 = lane & 31, hi = lane >> 5, row7 = lane & 7;
    int qw = blockIdx.y * 256 + w * 64;  // this wave's first q-row (64 rows/wave)

    int r = lane >> 3, c = lane & 7;
    int cs = ((c ^ r) << 3);
    const u16* gK0 = qkv + (size_t)(b * S_ + w * 16 + r) * QKVS + 1024 + h * DH_ + cs;
    const u16* gK1 = gK0 + (size_t)8 * QKVS;
    const u16* gV0 = vt + (size_t)(bh * DH_ + w * 16 + r) * S_ + cs;
    const u16* gV1 = gV0 + (size_t)8 * S_;

    auto stage = [&](int bb) {
        u16* lk = &Kb[bb][w * 16 * 64];
        u16* lv = &Vb[bb][w * 16 * 64];
        gl_lds16(gK0, lk);
        gl_lds16(gK1, lk + 8 * 64);
        gl_lds16(gV0, lv);
        gl_lds16(gV1, lv + 8 * 64);
        gK0 += (size_t)64 * QKVS; gK1 += (size_t)64 * QKVS;
        gV0 += 64; gV1 += 64;
    };

    // Q B-fragments for both subtiles: B[n = q][k = kc*16 + hi*8 + j]
    short8 qa0, qa1, qa2, qa3, qb0, qb1, qb2, qb3;
    {
        const u16* qpA = qkv + (size_t)(b * S_ + qw + l32) * QKVS + h * DH_ + hi * 8;
        qa0 = *(const short8*)(qpA);
        qa1 = *(const short8*)(qpA + 16);
        qa2 = *(const short8*)(qpA + 32);
        qa3 = *(const short8*)(qpA + 48);
        const u16* qpB = qpA + (size_t)32 * QKVS;
        qb0 = *(const short8*)(qpB);
        qb1 = *(const short8*)(qpB + 16);
        qb2 = *(const short8*)(qpB + 32);
        qb3 = *(const short8*)(qpB + 48);
    }

    floatx16 OA0, OA1, OB0, OB1;
#pragma unroll
    for (int i = 0; i < 16; ++i) { OA0[i] = 0.f; OA1[i] = 0.f; OB0[i] = 0.f; OB1[i] = 0.f; }
    float lra0 = 0.f, lra1 = 0.f, lrb0 = 0.f, lrb1 = 0.f;  // denominator partials

    int roff0 = l32 * 64;
    int roff1 = (32 + l32) * 64;

    stage(0);
    __syncthreads();

    const int NT = S_ / 64;
    for (int kt = 0; kt < NT; ++kt) {
        int cur = kt & 1;
        if (kt + 1 < NT) stage(cur ^ 1);

        const u16* Kc = Kb[cur];
        const u16* Vc = Vb[cur];

        short8 paA0, paA1, paA2, paA3, paB0, paB1, paB2, paB3;

        // ---- S^T tile 0 (keys 0..31): each K frag feeds both q-subtiles ----
        {
            floatx16 sA, sB;
#pragma unroll
            for (int i = 0; i < 16; ++i) { sA[i] = 0.f; sB[i] = 0.f; }
#pragma unroll
            for (int kc = 0; kc < 4; ++kc) {
                int ch = (((kc * 2 + hi) ^ row7) << 3);
                short8 ka = *(const short8*)&Kc[roff0 + ch];
                short8 qkA = (kc == 0) ? qa0 : (kc == 1) ? qa1 : (kc == 2) ? qa2 : qa3;
                short8 qkB = (kc == 0) ? qb0 : (kc == 1) ? qb1 : (kc == 2) ? qb2 : qb3;
                sA = mfma32(ka, qkA, sA);
                sB = mfma32(ka, qkB, sB);
            }
#pragma unroll
            for (int i = 0; i < 16; ++i) { sA[i] = exp2f_hw(sA[i]); sB[i] = exp2f_hw(sB[i]); }
#pragma unroll
            for (int i = 0; i < 16; i += 4) {
                lra0 += sA[i + 0] + sA[i + 1];
                lra1 += sA[i + 2] + sA[i + 3];
                lrb0 += sB[i + 0] + sB[i + 1];
                lrb1 += sB[i + 2] + sB[i + 3];
            }
            PACK8(sA, 0, paA0); PACK8(sA, 8, paA1);
            PACK8(sB, 0, paB0); PACK8(sB, 8, paB1);
        }

        // ---- S^T tile 1 (keys 32..63) ----
        {
            floatx16 sA, sB;
#pragma unroll
            for (int i = 0; i < 16; ++i) { sA[i] = 0.f; sB[i] = 0.f; }
#pragma unroll
            for (int kc = 0; kc < 4; ++kc) {
                int ch = (((kc * 2 + hi) ^ row7) << 3);
                short8 ka = *(const short8*)&Kc[roff1 + ch];
                short8 qkA = (kc == 0) ? qa0 : (kc == 1) ? qa1 : (kc == 2) ? qa2 : qa3;
                short8 qkB = (kc == 0) ? qb0 : (kc == 1) ? qb1 : (kc == 2) ? qb2 : qb3;
                sA = mfma32(ka, qkA, sA);
                sB = mfma32(ka, qkB, sB);
            }
#pragma unroll
            for (int i = 0; i < 16; ++i) { sA[i] = exp2f_hw(sA[i]); sB[i] = exp2f_hw(sB[i]); }
#pragma unroll
            for (int i = 0; i < 16; i += 4) {
                lra0 += sA[i + 0] + sA[i + 1];
                lra1 += sA[i + 2] + sA[i + 3];
                lrb0 += sB[i + 0] + sB[i + 1];
                lrb1 += sB[i + 2] + sB[i + 3];
            }
            PACK8(sA, 0, paA2); PACK8(sA, 8, paA3);
            PACK8(sB, 0, paB2); PACK8(sB, 8, paB3);
        }

        // ---- O += P @ V: each V frag feeds both q-subtiles ----
        {   // dh 0..31
            short8 vb0 = *(const short8*)&Vc[roff0 + (((0 + hi) ^ row7) << 3)];
            OA0 = mfma32(paA0, vb0, OA0);
            OB0 = mfma32(paB0, vb0, OB0);
            short8 vb1 = *(const short8*)&Vc[roff0 + (((2 + hi) ^ row7) << 3)];
            OA0 = mfma32(paA1, vb1, OA0);
            OB0 = mfma32(paB1, vb1, OB0);
            short8 vb2 = *(const short8*)&Vc[roff0 + (((4 + hi) ^ row7) << 3)];
            OA0 = mfma32(paA2, vb2, OA0);
            OB0 = mfma32(paB2, vb2, OB0);
            short8 vb3 = *(const short8*)&Vc[roff0 + (((6 + hi) ^ row7) << 3)];
            OA0 = mfma32(paA3, vb3, OA0);
            OB0 = mfma32(paB3, vb3, OB0);
        }
        {   // dh 32..63
            short8 vb0 = *(const short8*)&Vc[roff1 + (((0 + hi) ^ row7) << 3)];
            OA1 = mfma32(paA0, vb0, OA1);
            OB1 = mfma32(paB0, vb0, OB1);
            short8 vb1 = *(const short8*)&Vc[roff1 + (((2 + hi) ^ row7) << 3)];
            OA1 = mfma32(paA1, vb1, OA1);
            OB1 = mfma32(paB1, vb1, OB1);
            short8 vb2 = *(const short8*)&Vc[roff1 + (((4 + hi) ^ row7) << 3)];
            OA1 = mfma32(paA2, vb2, OA1);
            OB1 = mfma32(paB2, vb2, OB1);
            short8 vb3 = *(const short8*)&Vc[roff1 + (((6 + hi) ^ row7) << 3)];
            OA1 = mfma32(paA3, vb3, OA1);
            OB1 = mfma32(paB3, vb3, OB1);
        }

        __syncthreads();  // drains gl_lds (vmcnt) + protects buffer swap
    }

    // ---- epilogue: denom = self + other half-wave; O /= lsum; store bf16 ----
    float lrA = lra0 + lra1;
    float lrB = lrb0 + lrb1;
    lrA += __shfl_xor(lrA, 32);
    lrB += __shfl_xor(lrB, 32);
    float invA = 1.0f / lrA;   // for q = qw + l32
    float invB = 1.0f / lrB;   // for q = qw + 32 + l32
#pragma unroll
    for (int rr = 0; rr < 16; ++rr) {
        int rowq = (rr & 3) + 8 * (rr >> 2) + 4 * hi;  // C/D row -> q within subtile
        float ivA = __shfl(invA, rowq);
        float ivB = __shfl(invB, rowq);
        size_t baseA = (size_t)(b * S_ + qw + rowq) * D_ + h * DH_ + l32;
        ctx[baseA]      = f2b(OA0[rr] * ivA);
        ctx[baseA + 32] = f2b(OA1[rr] * ivA);
        size_t baseB = baseA + (size_t)32 * D_;
        ctx[baseB]      = f2b(OB0[rr] * ivB);
        ctx[baseB + 32] = f2b(OB1[rr] * ivB);
    }
}

// ---------- fused add + layernorm (one row of 1024 per block) ----------
__global__ __launch_bounds__(256) void add_ln(const float* __restrict__ a,
                                              const float* __restrict__ b,
                                              const float* __restrict__ g,
                                              const float* __restrict__ be,
                                              float* __restrict__ outF,
                                              u16* __restrict__ outB) {
    int row = blockIdx.x, tid = threadIdx.x;
    size_t base = (size_t)row * D_;
    float4 va = ((const float4*)(a + base))[tid];
    float4 vb = ((const float4*)(b + base))[tid];
    float x0 = va.x + vb.x, x1 = va.y + vb.y, x2 = va.z + vb.z, x3 = va.w + vb.w;
    float s1 = x0 + x1 + x2 + x3;
    float s2 = x0 * x0 + x1 * x1 + x2 * x2 + x3 * x3;
#pragma unroll
    for (int off = 32; off; off >>= 1) {
        s1 += __shfl_xor(s1, off);
        s2 += __shfl_xor(s2, off);
    }
    __shared__ float r1[4], r2[4];
    int w = tid >> 6, lane = tid & 63;
    if (lane == 0) { r1[w] = s1; r2[w] = s2; }
    __syncthreads();
    s1 = r1[0] + r1[1] + r1[2] + r1[3];
    s2 = r2[0] + r2[1] + r2[2] + r2[3];
    float mean = s1 * (1.0f / D_);
    float var = s2 * (1.0f / D_) - mean * mean;
    float inv = rsqrtf(var + 1e-6f);
    float4 vg = ((const float4*)g)[tid];
    float4 vbe = ((const float4*)be)[tid];
    float o0 = (x0 - mean) * inv * vg.x + vbe.x;
    float o1 = (x1 - mean) * inv * vg.y + vbe.y;
    float o2 = (x2 - mean) * inv * vg.z + vbe.z;
    float o3 = (x3 - mean) * inv * vg.w + vbe.w;
    float4 o; o.x = o0; o.y = o1; o.z = o2; o.w = o3;
    ((float4*)(outF + base))[tid] = o;
    if (outB) {
        ushort4 u;
        u.x = f2b(o0); u.y = f2b(o1); u.z = f2b(o2); u.w = f2b(o3);
        ((ushort4*)(outB + base))[tid] = u;
    }
}

extern "C" void kernel_launch(void* const* d_in, const int* in_sizes, int n_in,
                              void* d_out, int out_size, void* d_ws, size_t ws_size,
                              hipStream_t stream) {
    const float* x   = (const float*)d_in[0];
    const float* wq  = (const float*)d_in[1];
    const float* bq  = (const float*)d_in[2];
    const float* wk  = (const float*)d_in[3];
    const float* bk  = (const float*)d_in[4];
    const float* wv  = (const float*)d_in[5];
    const float* bv  = (const float*)d_in[6];
    const float* wo  = (const float*)d_in[7];
    const float* bo  = (const float*)d_in[8];
    const float* w1  = (const float*)d_in[9];
    const float* b1  = (const float*)d_in[10];
    const float* w2  = (const float*)d_in[11];
    const float* b2  = (const float*)d_in[12];
    const float* g1  = (const float*)d_in[13];
    const float* be1 = (const float*)d_in[14];
    const float* g2  = (const float*)d_in[15];
    const float* be2 = (const float*)d_in[16];
    float* out = (float*)d_out;
    char* ws = (char*)d_ws;
    const size_t MB = 1u << 20;

    // layout (185 MB total, with aliasing):
    u16* xb      = (u16*)(ws + 0);        // 16 MB (dead after QKV gemm)
    u16* wqkvT   = (u16*)(ws + 16 * MB);  // 6 MB [wq^T*QSCALE | wk^T | wv^T]
    u16* woT     = (u16*)(ws + 22 * MB);  // 2 MB
    u16* w1T     = (u16*)(ws + 24 * MB);  // 8 MB
    u16* w2T     = (u16*)(ws + 32 * MB);  // 8 MB
    float* qkvb  = (float*)(ws + 40 * MB);// 12 KB
    u16* qkv     = (u16*)(ws + 41 * MB);  // 48 MB (dead after attn)
    u16* vtb     = (u16*)(ws + 89 * MB);  // 16 MB (dead after attn)
    u16* ctxb    = (u16*)(ws + 105 * MB); // 16 MB
    float* attn_out = (float*)(ws + 121 * MB); // 32 MB (dead after add_ln1)
    float* out1     = (float*)(ws + 153 * MB); // 32 MB
    u16* out1b   = (u16*)(ws + 0);        // 16 MB, aliases dead xb
    u16* hidden  = (u16*)(ws + 41 * MB);  // 64 MB, aliases dead qkv+vtb after attn
    float* ffn2out = (float*)(ws + 121 * MB); // 32 MB, aliases dead attn_out

    // prep: cast + ALL weight transposes + bias concat in ONE launch
    prep<<<20492, 256, 0, stream>>>(x, xb, wq, wk, wv, wo, wqkvT, woT,
                                    w1, w1T, w2, w2T, bq, bk, bv, qkvb);

    // fused QKV projection: [8192,1024] @ [3072,1024]^T -> qkv [8192,3072]
    gemm256<<<dim3(12, 32), 512, 0, stream>>>(xb, wqkvT, qkvb, nullptr, qkv,
                                              B_ * S_, QKVS, D_, 0);
    transpose_v<<<dim3(S_ / 32, DH_ / 32, B_ * H_), dim3(32, 8), 0, stream>>>(qkv, vtb);

    // attention (flash-style, 64 q/wave, shared frag reads, KVBLK=64)
    attn_kernel<<<dim3(B_ * H_, S_ / 256), 256, 0, stream>>>(qkv, vtb, ctxb);

    // output projection: 256x128 tiles, grid (8,32) = 256 blocks = full machine,
    // no split-K partial round-trip; residual+LN in 2-input add_ln
    gemm256b<<<dim3(8, 32), 512, 0, stream>>>(ctxb, woT, bo, attn_out, nullptr,
                                              B_ * S_, D_, D_, 0);
    add_ln<<<B_ * S_, 256, 0, stream>>>(x, attn_out, g1, be1, out1, out1b);

    // FFN
    gemm256<<<dim3(16, 32), 512, 0, stream>>>(out1b, w1T, b1, nullptr, hidden,
                                              B_ * S_, F_, D_, 1);
    gemm256b<<<dim3(8, 32), 512, 0, stream>>>(hidden, w2T, b2, ffn2out, nullptr,
                                              B_ * S_, D_, F_, 0);
    add_ln<<<B_ * S_, 256, 0, stream>>>(out1, ffn2out, g2, be2, out, nullptr);
}

// Round 13
// 459.478 us; speedup vs baseline: 1.0837x; 1.0413x over previous
//
#include <hip/hip_runtime.h>

typedef unsigned short u16;
typedef unsigned int u32;

typedef __attribute__((ext_vector_type(8))) short short8;
typedef __attribute__((ext_vector_type(4))) float floatx4;
typedef __attribute__((ext_vector_type(16))) float floatx16;
typedef __attribute__((ext_vector_type(2))) unsigned int uint2v;
typedef __attribute__((ext_vector_type(4))) unsigned int uint4v;

// ---------- bf16 helpers ----------
static __device__ __forceinline__ u16 f2b(float f) {
    union { float f; u32 i; } v; v.f = f;
    u32 r = v.i + 0x7fffu + ((v.i >> 16) & 1u);
    return (u16)(r >> 16);
}
// 2^x via v_exp_f32
static __device__ __forceinline__ float exp2f_hw(float x) {
    return __builtin_amdgcn_exp2f(x);
}
// pack two f32 -> bf16x2 dword (RNE) in one instruction
static __device__ __forceinline__ u32 cvtpk(float lo, float hi) {
    u32 r;
    asm("v_cvt_pk_bf16_f32 %0, %1, %2" : "=v"(r) : "v"(lo), "v"(hi));
    return r;
}

static __device__ __forceinline__ floatx4 mfma16(short8 a, short8 b, floatx4 c) {
    return __builtin_amdgcn_mfma_f32_16x16x32_bf16(a, b, c, 0, 0, 0);
}
static __device__ __forceinline__ floatx16 mfma32(short8 a, short8 b, floatx16 c) {
    return __builtin_amdgcn_mfma_f32_32x32x16_bf16(a, b, c, 0, 0, 0);
}

// async global->LDS, 16B per lane; LDS dest must be wave-uniform base (HW adds lane*16)
typedef __attribute__((address_space(1))) const void gas_void;
typedef __attribute__((address_space(3))) void las_void;
static __device__ __forceinline__ void gl_lds16(const void* g, void* l) {
    __builtin_amdgcn_global_load_lds((gas_void*)g, (las_void*)l, 16, 0, 0);
}

// counted vmcnt wait (T4) + raw barrier, both with compiler memory fence
template<int N> static __device__ __forceinline__ void vmw() {
    if constexpr (N == 0)      asm volatile("s_waitcnt vmcnt(0)" ::: "memory");
    else if constexpr (N == 2) asm volatile("s_waitcnt vmcnt(2)" ::: "memory");
    else if constexpr (N == 4) asm volatile("s_waitcnt vmcnt(4)" ::: "memory");
}
#define SBAR() asm volatile("s_barrier" ::: "memory")

#define B_ 4
#define S_ 2048
#define D_ 1024
#define H_ 16
#define DH_ 64
#define F_ 4096
#define QKVS 3072   // row stride of fused qkv output

// (1/8) * log2(e), folded into wq/bq so logits come out in exp2 domain
#define QSCALE 0.18033688011112042f

// ---------- mega-prep: cast_b + 6 weight transposes + concat_bias, ONE launch ----
__global__ __launch_bounds__(256) void prep(
    const float* __restrict__ x, u16* __restrict__ xb,
    const float* __restrict__ wq, const float* __restrict__ wk,
    const float* __restrict__ wv, const float* __restrict__ wo,
    u16* __restrict__ wqkvT, u16* __restrict__ woT,
    const float* __restrict__ w1, u16* __restrict__ w1T,
    const float* __restrict__ w2, u16* __restrict__ w2T,
    const float* __restrict__ bq, const float* __restrict__ bk,
    const float* __restrict__ bv, float* __restrict__ qkvb) {
    int bid = blockIdx.x, tid = threadIdx.x;

    if (bid < 8192) {   // cast x (fp32) -> xb (bf16), 4 elems/thread, exact cover
        int id = bid * 256 + tid;
        float4 v = ((const float4*)x)[id];
        ushort4 u;
        u.x = f2b(v.x); u.y = f2b(v.y); u.z = f2b(v.z); u.w = f2b(v.w);
        ((ushort4*)xb)[id] = u;
        return;
    }
    bid -= 8192;

    if (bid >= 12288) { // concat + scale bias: [bq*QSCALE | bk | bv] (12 blocks)
        int i = (bid - 12288) * 256 + tid;
        float v;
        if (i < 1024) v = bq[i] * QSCALE;
        else if (i < 2048) v = bk[i - 1024];
        else v = bv[i - 2048];
        qkvb[i] = v;
        return;
    }

    // transpose+cast partitions (32x32 tile per block, 256 thr as 32x8)
    __shared__ float t[32][33];
    int x32 = tid & 31, y8 = tid >> 5;
    const float* in; u16* outp; float scale = 1.0f; int R, C, bx, by;
    if (bid < 4096) {          // four 1024x1024 weights
        int z = bid >> 10, rem = bid & 1023;
        bx = rem & 31; by = rem >> 5;
        in = (z == 0) ? wq : (z == 1) ? wk : (z == 2) ? wv : wo;
        outp = (z == 0) ? wqkvT : (z == 1) ? (wqkvT + 1024 * 1024)
             : (z == 2) ? (wqkvT + 2048 * 1024) : woT;
        scale = (z == 0) ? QSCALE : 1.0f;
        R = 1024; C = 1024;
    } else if (bid < 8192) {   // w1 [1024 x 4096]
        int rem = bid - 4096; bx = rem & 127; by = rem >> 7;
        in = w1; outp = w1T; R = 1024; C = 4096;
    } else {                   // w2 [4096 x 1024]
        int rem = bid - 8192; bx = rem & 31; by = rem >> 5;
        in = w2; outp = w2T; R = 4096; C = 1024;
    }
#pragma unroll
    for (int i = 0; i < 4; ++i) {
        int r = by * 32 + y8 + i * 8;
        t[y8 + i * 8][x32] = in[(size_t)r * C + bx * 32 + x32];
    }
    __syncthreads();
#pragma unroll
    for (int i = 0; i < 4; ++i) {
        int c = bx * 32 + y8 + i * 8;
        outp[(size_t)c * R + by * 32 + x32] = f2b(t[x32][y8 + i * 8] * scale);
    }
}

// ---------- transpose V: qkv[B*S, 3072] cols 2048.. -> vt [B,H,DH,S] bf16 ----------
__global__ void transpose_v(const u16* __restrict__ qkv, u16* __restrict__ vt) {
    __shared__ u16 t[32][33];
    int bh = blockIdx.z; int b = bh >> 4, h = bh & 15;
    int s0 = blockIdx.x * 32, d0 = blockIdx.y * 32;
    int x = threadIdx.x, y = threadIdx.y;  // 32x8
#pragma unroll
    for (int i = 0; i < 4; ++i)
        t[y + i * 8][x] =
            qkv[(size_t)(b * S_ + s0 + y + i * 8) * QKVS + 2048 + h * DH_ + d0 + x];
    __syncthreads();
#pragma unroll
    for (int i = 0; i < 4; ++i)
        vt[((size_t)bh * DH_ + d0 + y + i * 8) * S_ + s0 + x] = t[x][y + i * 8];
}

// ---------- gemm256 v4: 256x256 tile, 8-phase, slot-disciplined staging ----------
// (see round-7 comments: WAR-safe prefetch distance, vmcnt(2) at ph4/ph8 only,
// one barrier per phase, XOR-swizzled 8KB chunks). Used where the grid makes
// FULL device passes: FFN1 (16,32)=512 blocks = 2 exact passes.
#define MFMA16X(MH)                                                        \
    __builtin_amdgcn_s_setprio(1);                                         \
    acc[(MH)*4+0][0] = mfma16(af0, bf0, acc[(MH)*4+0][0]);                 \
    acc[(MH)*4+0][1] = mfma16(af0, bf1, acc[(MH)*4+0][1]);                 \
    acc[(MH)*4+0][2] = mfma16(af0, bf2, acc[(MH)*4+0][2]);                 \
    acc[(MH)*4+0][3] = mfma16(af0, bf3, acc[(MH)*4+0][3]);                 \
    acc[(MH)*4+1][0] = mfma16(af1, bf0, acc[(MH)*4+1][0]);                 \
    acc[(MH)*4+1][1] = mfma16(af1, bf1, acc[(MH)*4+1][1]);                 \
    acc[(MH)*4+1][2] = mfma16(af1, bf2, acc[(MH)*4+1][2]);                 \
    acc[(MH)*4+1][3] = mfma16(af1, bf3, acc[(MH)*4+1][3]);                 \
    acc[(MH)*4+2][0] = mfma16(af2, bf0, acc[(MH)*4+2][0]);                 \
    acc[(MH)*4+2][1] = mfma16(af2, bf1, acc[(MH)*4+2][1]);                 \
    acc[(MH)*4+2][2] = mfma16(af2, bf2, acc[(MH)*4+2][2]);                 \
    acc[(MH)*4+2][3] = mfma16(af2, bf3, acc[(MH)*4+2][3]);                 \
    acc[(MH)*4+3][0] = mfma16(af3, bf0, acc[(MH)*4+3][0]);                 \
    acc[(MH)*4+3][1] = mfma16(af3, bf1, acc[(MH)*4+3][1]);                 \
    acc[(MH)*4+3][2] = mfma16(af3, bf2, acc[(MH)*4+3][2]);                 \
    acc[(MH)*4+3][3] = mfma16(af3, bf3, acc[(MH)*4+3][3]);                 \
    __builtin_amdgcn_s_setprio(0);

#define PPAIR(P, KH, STa, Wa, STb, Wb) {                                   \
    int ro = l * 64 + ((((KH) * 4 + quad) ^ l7) << 3);                     \
    const u16* bBp = &smem[32768 + (P) * 16384 + wc * 4096];               \
    short8 bf0 = *(const short8*)&bBp[ro];                                 \
    short8 bf1 = *(const short8*)&bBp[ro + 1024];                          \
    short8 bf2 = *(const short8*)&bBp[ro + 2048];                          \
    short8 bf3 = *(const short8*)&bBp[ro + 3072];                          \
    {   const u16* bAp = &smem[(P) * 16384 + (wr * 2 + 0) * 4096];         \
        short8 af0 = *(const short8*)&bAp[ro];                             \
        short8 af1 = *(const short8*)&bAp[ro + 1024];                      \
        short8 af2 = *(const short8*)&bAp[ro + 2048];                      \
        short8 af3 = *(const short8*)&bAp[ro + 3072];                      \
        STa; Wa;                                                           \
        MFMA16X(0)                                                         \
        SBAR();                                                            \
    }                                                                      \
    {   const u16* bAp = &smem[(P) * 16384 + (wr * 2 + 1) * 4096];         \
        short8 af0 = *(const short8*)&bAp[ro];                             \
        short8 af1 = *(const short8*)&bAp[ro + 1024];                      \
        short8 af2 = *(const short8*)&bAp[ro + 2048];                      \
        short8 af3 = *(const short8*)&bAp[ro + 3072];                      \
        STb; Wb;                                                           \
        MFMA16X(1)                                                         \
        SBAR();                                                            \
    } }

__global__ __launch_bounds__(512) void gemm256(const u16* __restrict__ A,
                                               const u16* __restrict__ Bt,
                                               const float* __restrict__ bias,
                                               float* __restrict__ outF,
                                               u16* __restrict__ outB,
                                               int M, int N, int K, int relu) {
    __shared__ __align__(16) u16 smem[65536];   // 128 KB

    int tid = threadIdx.x;
    int w = tid >> 6, lane = tid & 63, quad = lane >> 4, l = lane & 15;
    int wr = w >> 2, wc = w & 3;
    int l7 = l & 7;

    // XCD-aware bijective block swizzle (nwg % 8 == 0 for all our shapes)
    int nbN = gridDim.x, nwg = gridDim.x * gridDim.y;
    int flat = blockIdx.y * gridDim.x + blockIdx.x;
    int swz = (flat & 7) * (nwg >> 3) + (flat >> 3);
    int bM = swz / nbN, bN = swz % nbN;

    floatx4 acc[8][4];
#pragma unroll
    for (int i = 0; i < 8; ++i)
#pragma unroll
        for (int j = 0; j < 4; ++j) acc[i][j] = (floatx4){0.f, 0.f, 0.f, 0.f};

    int rT = tid >> 3, cT = tid & 7;
    int cg8 = ((cT ^ (rT & 7)) << 3);
    const u16* gA0 = A + (size_t)(bM * 256 + rT) * K + cg8;
    const u16* gB0 = Bt + (size_t)(bN * 256 + rT) * K + cg8;

    auto stA = [&](int p, int ch, int t) {
        gl_lds16(gA0 + (size_t)(ch * 64) * K + t * 64,
                 (void*)&smem[p * 16384 + ch * 4096 + (w << 9)]);
    };
    auto stB = [&](int p, int hb, int t) {
        gl_lds16(gB0 + (size_t)(hb * 64) * K + t * 64,
                 (void*)&smem[32768 + p * 16384 + hb * 4096 + (w << 9)]);
    };

    // prologue: tile0 full -> P0, tile1 {A0,A2} -> P1; drain t0 (leave t1's 2)
    stA(0, 0, 0); stA(0, 1, 0); stA(0, 2, 0); stA(0, 3, 0);
    stB(0, 0, 0); stB(0, 1, 0); stB(0, 2, 0); stB(0, 3, 0);
    stA(1, 0, 1); stA(1, 2, 1);
    vmw<2>(); SBAR();

    const int NI = K >> 7;   // iterations of 2 K-tiles
    for (int j = 0; j < NI - 1; ++j) {
        int to = 2 * j + 1, te = 2 * j + 2, tn = 2 * j + 3;
        PPAIR(0, 0, (stA(1,1,to), stA(1,3,to), stB(1,0,to), stB(1,1,to)), ((void)0),
                    (stB(1,2,to), stB(1,3,to)), ((void)0))
        PPAIR(0, 1, ((void)0), ((void)0),
                    (stA(0,0,te), stA(0,2,te)), vmw<2>())
        PPAIR(1, 0, (stA(0,1,te), stA(0,3,te), stB(0,0,te), stB(0,1,te)), ((void)0),
                    (stB(0,2,te), stB(0,3,te)), ((void)0))
        PPAIR(1, 1, ((void)0), ((void)0),
                    (stA(1,0,tn), stA(1,2,tn)), vmw<2>())
    }
    {   // final iteration: finish P1<-KT-1 at ph1/ph2, drain all at ph4
        int to = 2 * (NI - 1) + 1;
        PPAIR(0, 0, (stA(1,1,to), stA(1,3,to), stB(1,0,to), stB(1,1,to)), ((void)0),
                    (stB(1,2,to), stB(1,3,to)), ((void)0))
        PPAIR(0, 1, ((void)0), ((void)0), ((void)0), vmw<0>())
        PPAIR(1, 0, ((void)0), ((void)0), ((void)0), ((void)0))
        PPAIR(1, 1, ((void)0), ((void)0), ((void)0), ((void)0))
    }

    // epilogue: row-major store order (nt innermost); bias hoisted
    float bv4[4];
#pragma unroll
    for (int nt = 0; nt < 4; ++nt) {
        int colg = bN * 256 + wc * 64 + nt * 16 + l;
        bv4[nt] = bias ? bias[colg] : 0.f;
    }
#pragma unroll
    for (int mt = 0; mt < 8; ++mt) {
#pragma unroll
        for (int rr = 0; rr < 4; ++rr) {
            int rowg = bM * 256 + wr * 128 + mt * 16 + quad * 4 + rr;
            size_t rb = (size_t)rowg * N + bN * 256 + wc * 64 + l;
#pragma unroll
            for (int nt = 0; nt < 4; ++nt) {
                float v = acc[mt][nt][rr] + bv4[nt];
                if (relu) v = fmaxf(v, 0.f);
                if (outF) outF[rb + nt * 16] = v;
                if (outB) outB[rb + nt * 16] = f2b(v);
            }
        }
    }
}

// ---------- gemm256b: 256x128 tile (full-device-pass grids for N%256 shapes) ----
// Subset of the v4 schedule (A-side identical; B = 2 chunks/K-tile). LDS 96 KB.
// Used for: QKV (24,32)=768 blocks = 3 exact passes (v12 A/B: 256-wide tile's
// 384-block grid = 1.5 passes left half the machine idle for 1/3 of dispatch ->
// 93us, 554 TF); WO/FFN2 (8,32)=256 = 1 exact pass.
#define MFMA8X(MH)                                                         \
    __builtin_amdgcn_s_setprio(1);                                         \
    acc[(MH)*4+0][0] = mfma16(af0, bf0, acc[(MH)*4+0][0]);                 \
    acc[(MH)*4+0][1] = mfma16(af0, bf1, acc[(MH)*4+0][1]);                 \
    acc[(MH)*4+1][0] = mfma16(af1, bf0, acc[(MH)*4+1][0]);                 \
    acc[(MH)*4+1][1] = mfma16(af1, bf1, acc[(MH)*4+1][1]);                 \
    acc[(MH)*4+2][0] = mfma16(af2, bf0, acc[(MH)*4+2][0]);                 \
    acc[(MH)*4+2][1] = mfma16(af2, bf1, acc[(MH)*4+2][1]);                 \
    acc[(MH)*4+3][0] = mfma16(af3, bf0, acc[(MH)*4+3][0]);                 \
    acc[(MH)*4+3][1] = mfma16(af3, bf1, acc[(MH)*4+3][1]);                 \
    __builtin_amdgcn_s_setprio(0);

#define PPAIRB(P, KH, STa, Wa, STb, Wb) {                                  \
    int sw = (((KH) * 4 + quad) ^ l7) << 3;                                \
    int ro = l * 64 + sw;                                                  \
    int rob = ((wc & 1) * 32 + l) * 64 + sw;                               \
    const u16* bBp = &smem[32768 + (P) * 8192 + (wc >> 1) * 4096];         \
    short8 bf0 = *(const short8*)&bBp[rob];                                \
    short8 bf1 = *(const short8*)&bBp[rob + 1024];                         \
    {   const u16* bAp = &smem[(P) * 16384 + (wr * 2 + 0) * 4096];         \
        short8 af0 = *(const short8*)&bAp[ro];                             \
        short8 af1 = *(const short8*)&bAp[ro + 1024];                      \
        short8 af2 = *(const short8*)&bAp[ro + 2048];                      \
        short8 af3 = *(const short8*)&bAp[ro + 3072];                      \
        STa; Wa;                                                           \
        MFMA8X(0)                                                          \
        SBAR();                                                            \
    }                                                                      \
    {   const u16* bAp = &smem[(P) * 16384 + (wr * 2 + 1) * 4096];         \
        short8 af0 = *(const short8*)&bAp[ro];                             \
        short8 af1 = *(const short8*)&bAp[ro + 1024];                      \
        short8 af2 = *(const short8*)&bAp[ro + 2048];                      \
        short8 af3 = *(const short8*)&bAp[ro + 3072];                      \
        STb; Wb;                                                           \
        MFMA8X(1)                                                          \
        SBAR();                                                            \
    } }

__global__ __launch_bounds__(512) void gemm256b(const u16* __restrict__ A,
                                                const u16* __restrict__ Bt,
                                                const float* __restrict__ bias,
                                                float* __restrict__ outF,
                                                u16* __restrict__ outB,
                                                int M, int N, int K, int relu) {
    __shared__ __align__(16) u16 smem[49152];   // 96 KB: A 64KB + B 32KB

    int tid = threadIdx.x;
    int w = tid >> 6, lane = tid & 63, quad = lane >> 4, l = lane & 15;
    int wr = w >> 2, wc = w & 3;
    int l7 = l & 7;

    // XCD-aware bijective block swizzle (nwg % 8 == 0)
    int nbN = gridDim.x, nwg = gridDim.x * gridDim.y;
    int flat = blockIdx.y * gridDim.x + blockIdx.x;
    int swz = (flat & 7) * (nwg >> 3) + (flat >> 3);
    int bM = swz / nbN, bN = swz % nbN;

    floatx4 acc[8][2];
#pragma unroll
    for (int i = 0; i < 8; ++i)
#pragma unroll
        for (int j = 0; j < 2; ++j) acc[i][j] = (floatx4){0.f, 0.f, 0.f, 0.f};

    int rT = tid >> 3, cT = tid & 7;
    int cg8 = ((cT ^ (rT & 7)) << 3);
    const u16* gA0 = A + (size_t)(bM * 256 + rT) * K + cg8;
    const u16* gB0 = Bt + (size_t)(bN * 128 + rT) * K + cg8;

    auto stA = [&](int p, int ch, int t) {
        gl_lds16(gA0 + (size_t)(ch * 64) * K + t * 64,
                 (void*)&smem[p * 16384 + ch * 4096 + (w << 9)]);
    };
    auto stB = [&](int p, int hb, int t) {
        gl_lds16(gB0 + (size_t)(hb * 64) * K + t * 64,
                 (void*)&smem[32768 + p * 8192 + hb * 4096 + (w << 9)]);
    };

    // prologue: tile0 (6 chunks) -> P0, tile1 {A0,A2} -> P1; drain t0
    stA(0, 0, 0); stA(0, 1, 0); stA(0, 2, 0); stA(0, 3, 0);
    stB(0, 0, 0); stB(0, 1, 0);
    stA(1, 0, 1); stA(1, 2, 1);
    vmw<2>(); SBAR();

    const int NI = K >> 7;   // iterations of 2 K-tiles
    for (int j = 0; j < NI - 1; ++j) {
        int to = 2 * j + 1, te = 2 * j + 2, tn = 2 * j + 3;
        PPAIRB(0, 0, (stA(1,1,to), stA(1,3,to), stB(1,0,to), stB(1,1,to)), ((void)0),
                     ((void)0), ((void)0))
        PPAIRB(0, 1, ((void)0), ((void)0),
                     (stA(0,0,te), stA(0,2,te)), vmw<2>())
        PPAIRB(1, 0, (stA(0,1,te), stA(0,3,te), stB(0,0,te), stB(0,1,te)), ((void)0),
                     ((void)0), ((void)0))
        PPAIRB(1, 1, ((void)0), ((void)0),
                     (stA(1,0,tn), stA(1,2,tn)), vmw<2>())
    }
    {   // final iteration: finish P1<-KT-1 at ph1, drain all at ph4
        int to = 2 * (NI - 1) + 1;
        PPAIRB(0, 0, (stA(1,1,to), stA(1,3,to), stB(1,0,to), stB(1,1,to)), ((void)0),
                     ((void)0), ((void)0))
        PPAIRB(0, 1, ((void)0), ((void)0), ((void)0), vmw<0>())
        PPAIRB(1, 0, ((void)0), ((void)0), ((void)0), ((void)0))
        PPAIRB(1, 1, ((void)0), ((void)0), ((void)0), ((void)0))
    }

    // epilogue: row-major store order (nt innermost); bias hoisted
    float bv2[2];
#pragma unroll
    for (int nt = 0; nt < 2; ++nt) {
        int colg = bN * 128 + wc * 32 + nt * 16 + l;
        bv2[nt] = bias ? bias[colg] : 0.f;
    }
#pragma unroll
    for (int mt = 0; mt < 8; ++mt) {
#pragma unroll
        for (int rr = 0; rr < 4; ++rr) {
            int rowg = bM * 256 + wr * 128 + mt * 16 + quad * 4 + rr;
            size_t rb = (size_t)rowg * N + bN * 128 + wc * 32 + l;
#pragma unroll
            for (int nt = 0; nt < 2; ++nt) {
                float v = acc[mt][nt][rr] + bv2[nt];
                if (relu) v = fmaxf(v, 0.f);
                if (outF) outF[rb + nt * 16] = v;
                if (outB) outB[rb + nt * 16] = f2b(v);
            }
        }
    }
}

// ---------- flash attention v7 (KVBLK=64, measured-best 78us config) ------------
#define PACK8(sv, rb, dst) {                                                   \
    u32 pa_ = cvtpk(sv[rb + 0], sv[rb + 1]), pb_ = cvtpk(sv[rb + 4], sv[rb + 5]); \
    u32 pc_ = cvtpk(sv[rb + 2], sv[rb + 3]), pd_ = cvtpk(sv[rb + 6], sv[rb + 7]); \
    uint2v t0_ = __builtin_amdgcn_permlane32_swap(pa_, pb_, 0, 0);             \
    uint2v t1_ = __builtin_amdgcn_permlane32_swap(pc_, pd_, 0, 0);             \
    union { uint4v u; short8 s8; } cv_;                                        \
    cv_.u = (uint4v){t0_[0], t1_[0], t0_[1], t1_[1]};                          \
    dst = cv_.s8; }

__global__ __launch_bounds__(256, 2) void attn_kernel(const u16* __restrict__ qkv,
                                                      const u16* __restrict__ vt,
                                                      u16* __restrict__ ctx) {
    __shared__ __align__(16) u16 Kb[2][64 * 64];   // 16 KB
    __shared__ __align__(16) u16 Vb[2][64 * 64];   // 16 KB

    int bh = blockIdx.x; int b = bh >> 4, h = bh & 15;
    int tid = threadIdx.x;
    int w = tid >> 6, lane = tid & 63;
    int l32 = lane & 31, hi = lane >> 5, row7 = lane & 7;
    int qw = blockIdx.y * 256 + w * 64;  // this wave's first q-row (64 rows/wave)

    int r = lane >> 3, c = lane & 7;
    int cs = ((c ^ r) << 3);
    const u16* gK0 = qkv + (size_t)(b * S_ + w * 16 + r) * QKVS + 1024 + h * DH_ + cs;
    const u16* gK1 = gK0 + (size_t)8 * QKVS;
    const u16* gV0 = vt + (size_t)(bh * DH_ + w * 16 + r) * S_ + cs;
    const u16* gV1 = gV0 + (size_t)8 * S_;

    auto stage = [&](int bb) {
        u16* lk = &Kb[bb][w * 16 * 64];
        u16* lv = &Vb[bb][w * 16 * 64];
        gl_lds16(gK0, lk);
        gl_lds16(gK1, lk + 8 * 64);
        gl_lds16(gV0, lv);
        gl_lds16(gV1, lv + 8 * 64);
        gK0 += (size_t)64 * QKVS; gK1 += (size_t)64 * QKVS;
        gV0 += 64; gV1 += 64;
    };

    // Q B-fragments for both subtiles: B[n = q][k = kc*16 + hi*8 + j]
    short8 qa0, qa1, qa2, qa3, qb0, qb1, qb2, qb3;
    {
        const u16* qpA = qkv + (size_t)(b * S_ + qw + l32) * QKVS + h * DH_ + hi * 8;
        qa0 = *(const short8*)(qpA);
        qa1 = *(const short8*)(qpA + 16);
        qa2 = *(const short8*)(qpA + 32);
        qa3 = *(const short8*)(qpA + 48);
        const u16* qpB = qpA + (size_t)32 * QKVS;
        qb0 = *(const short8*)(qpB);
        qb1 = *(const short8*)(qpB + 16);
        qb2 = *(const short8*)(qpB + 32);
        qb3 = *(const short8*)(qpB + 48);
    }

    floatx16 OA0, OA1, OB0, OB1;
#pragma unroll
    for (int i = 0; i < 16; ++i) { OA0[i] = 0.f; OA1[i] = 0.f; OB0[i] = 0.f; OB1[i] = 0.f; }
    float lra0 = 0.f, lra1 = 0.f, lrb0 = 0.f, lrb1 = 0.f;  // denominator partials

    int roff0 = l32 * 64;
    int roff1 = (32 + l32) * 64;

    stage(0);
    __syncthreads();

    const int NT = S_ / 64;
    for (int kt = 0; kt < NT; ++kt) {
        int cur = kt & 1;
        if (kt + 1 < NT) stage(cur ^ 1);

        const u16* Kc = Kb[cur];
        const u16* Vc = Vb[cur];

        short8 paA0, paA1, paA2, paA3, paB0, paB1, paB2, paB3;

        // ---- S^T tile 0 (keys 0..31): each K frag feeds both q-subtiles ----
        {
            floatx16 sA, sB;
#pragma unroll
            for (int i = 0; i < 16; ++i) { sA[i] = 0.f; sB[i] = 0.f; }
#pragma unroll
            for (int kc = 0; kc < 4; ++kc) {
                int ch = (((kc * 2 + hi) ^ row7) << 3);
                short8 ka = *(const short8*)&Kc[roff0 + ch];
                short8 qkA = (kc == 0) ? qa0 : (kc == 1) ? qa1 : (kc == 2) ? qa2 : qa3;
                short8 qkB = (kc == 0) ? qb0 : (kc == 1) ? qb1 : (kc == 2) ? qb2 : qb3;
                sA = mfma32(ka, qkA, sA);
                sB = mfma32(ka, qkB, sB);
            }
#pragma unroll
            for (int i = 0; i < 16; ++i) { sA[i] = exp2f_hw(sA[i]); sB[i] = exp2f_hw(sB[i]); }
#pragma unroll
            for (int i = 0; i < 16; i += 4) {
                lra0 += sA[i + 0] + sA[i + 1];
                lra1 += sA[i + 2] + sA[i + 3];
                lrb0 += sB[i + 0] + sB[i + 1];
                lrb1 += sB[i + 2] + sB[i + 3];
            }
            PACK8(sA, 0, paA0); PACK8(sA, 8, paA1);
            PACK8(sB, 0, paB0); PACK8(sB, 8, paB1);
        }

        // ---- S^T tile 1 (keys 32..63) ----
        {
            floatx16 sA, sB;
#pragma unroll
            for (int i = 0; i < 16; ++i) { sA[i] = 0.f; sB[i] = 0.f; }
#pragma unroll
            for (int kc = 0; kc < 4; ++kc) {
                int ch = (((kc * 2 + hi) ^ row7) << 3);
                short8 ka = *(const short8*)&Kc[roff1 + ch];
                short8 qkA = (kc == 0) ? qa0 : (kc == 1) ? qa1 : (kc == 2) ? qa2 : qa3;
                short8 qkB = (kc == 0) ? qb0 : (kc == 1) ? qb1 : (kc == 2) ? qb2 : qb3;
                sA = mfma32(ka, qkA, sA);
                sB = mfma32(ka, qkB, sB);
            }
#pragma unroll
            for (int i = 0; i < 16; ++i) { sA[i] = exp2f_hw(sA[i]); sB[i] = exp2f_hw(sB[i]); }
#pragma unroll
            for (int i = 0; i < 16; i += 4) {
                lra0 += sA[i + 0] + sA[i + 1];
                lra1 += sA[i + 2] + sA[i + 3];
                lrb0 += sB[i + 0] + sB[i + 1];
                lrb1 += sB[i + 2] + sB[i + 3];
            }
            PACK8(sA, 0, paA2); PACK8(sA, 8, paA3);
            PACK8(sB, 0, paB2); PACK8(sB, 8, paB3);
        }

        // ---- O += P @ V: each V frag feeds both q-subtiles ----
        {   // dh 0..31
            short8 vb0 = *(const short8*)&Vc[roff0 + (((0 + hi) ^ row7) << 3)];
            OA0 = mfma32(paA0, vb0, OA0);
            OB0 = mfma32(paB0, vb0, OB0);
            short8 vb1 = *(const short8*)&Vc[roff0 + (((2 + hi) ^ row7) << 3)];
            OA0 = mfma32(paA1, vb1, OA0);
            OB0 = mfma32(paB1, vb1, OB0);
            short8 vb2 = *(const short8*)&Vc[roff0 + (((4 + hi) ^ row7) << 3)];
            OA0 = mfma32(paA2, vb2, OA0);
            OB0 = mfma32(paB2, vb2, OB0);
            short8 vb3 = *(const short8*)&Vc[roff0 + (((6 + hi) ^ row7) << 3)];
            OA0 = mfma32(paA3, vb3, OA0);
            OB0 = mfma32(paB3, vb3, OB0);
        }
        {   // dh 32..63
            short8 vb0 = *(const short8*)&Vc[roff1 + (((0 + hi) ^ row7) << 3)];
            OA1 = mfma32(paA0, vb0, OA1);
            OB1 = mfma32(paB0, vb0, OB1);
            short8 vb1 = *(const short8*)&Vc[roff1 + (((2 + hi) ^ row7) << 3)];
            OA1 = mfma32(paA1, vb1, OA1);
            OB1 = mfma32(paB1, vb1, OB1);
            short8 vb2 = *(const short8*)&Vc[roff1 + (((4 + hi) ^ row7) << 3)];
            OA1 = mfma32(paA2, vb2, OA1);
            OB1 = mfma32(paB2, vb2, OB1);
            short8 vb3 = *(const short8*)&Vc[roff1 + (((6 + hi) ^ row7) << 3)];
            OA1 = mfma32(paA3, vb3, OA1);
            OB1 = mfma32(paB3, vb3, OB1);
        }

        __syncthreads();  // drains gl_lds (vmcnt) + protects buffer swap
    }

    // ---- epilogue: denom = self + other half-wave; O /= lsum; store bf16 ----
    float lrA = lra0 + lra1;
    float lrB = lrb0 + lrb1;
    lrA += __shfl_xor(lrA, 32);
    lrB += __shfl_xor(lrB, 32);
    float invA = 1.0f / lrA;   // for q = qw + l32
    float invB = 1.0f / lrB;   // for q = qw + 32 + l32
#pragma unroll
    for (int rr = 0; rr < 16; ++rr) {
        int rowq = (rr & 3) + 8 * (rr >> 2) + 4 * hi;  // C/D row -> q within subtile
        float ivA = __shfl(invA, rowq);
        float ivB = __shfl(invB, rowq);
        size_t baseA = (size_t)(b * S_ + qw + rowq) * D_ + h * DH_ + l32;
        ctx[baseA]      = f2b(OA0[rr] * ivA);
        ctx[baseA + 32] = f2b(OA1[rr] * ivA);
        size_t baseB = baseA + (size_t)32 * D_;
        ctx[baseB]      = f2b(OB0[rr] * ivB);
        ctx[baseB + 32] = f2b(OB1[rr] * ivB);
    }
}

// ---------- fused add + layernorm (one row of 1024 per block) ----------
__global__ __launch_bounds__(256) void add_ln(const float* __restrict__ a,
                                              const float* __restrict__ b,
                                              const float* __restrict__ g,
                                              const float* __restrict__ be,
                                              float* __restrict__ outF,
                                              u16* __restrict__ outB) {
    int row = blockIdx.x, tid = threadIdx.x;
    size_t base = (size_t)row * D_;
    float4 va = ((const float4*)(a + base))[tid];
    float4 vb = ((const float4*)(b + base))[tid];
    float x0 = va.x + vb.x, x1 = va.y + vb.y, x2 = va.z + vb.z, x3 = va.w + vb.w;
    float s1 = x0 + x1 + x2 + x3;
    float s2 = x0 * x0 + x1 * x1 + x2 * x2 + x3 * x3;
#pragma unroll
    for (int off = 32; off; off >>= 1) {
        s1 += __shfl_xor(s1, off);
        s2 += __shfl_xor(s2, off);
    }
    __shared__ float r1[4], r2[4];
    int w = tid >> 6, lane = tid & 63;
    if (lane == 0) { r1[w] = s1; r2[w] = s2; }
    __syncthreads();
    s1 = r1[0] + r1[1] + r1[2] + r1[3];
    s2 = r2[0] + r2[1] + r2[2] + r2[3];
    float mean = s1 * (1.0f / D_);
    float var = s2 * (1.0f / D_) - mean * mean;
    float inv = rsqrtf(var + 1e-6f);
    float4 vg = ((const float4*)g)[tid];
    float4 vbe = ((const float4*)be)[tid];
    float o0 = (x0 - mean) * inv * vg.x + vbe.x;
    float o1 = (x1 - mean) * inv * vg.y + vbe.y;
    float o2 = (x2 - mean) * inv * vg.z + vbe.z;
    float o3 = (x3 - mean) * inv * vg.w + vbe.w;
    float4 o; o.x = o0; o.y = o1; o.z = o2; o.w = o3;
    ((float4*)(outF + base))[tid] = o;
    if (outB) {
        ushort4 u;
        u.x = f2b(o0); u.y = f2b(o1); u.z = f2b(o2); u.w = f2b(o3);
        ((ushort4*)(outB + base))[tid] = u;
    }
}

extern "C" void kernel_launch(void* const* d_in, const int* in_sizes, int n_in,
                              void* d_out, int out_size, void* d_ws, size_t ws_size,
                              hipStream_t stream) {
    const float* x   = (const float*)d_in[0];
    const float* wq  = (const float*)d_in[1];
    const float* bq  = (const float*)d_in[2];
    const float* wk  = (const float*)d_in[3];
    const float* bk  = (const float*)d_in[4];
    const float* wv  = (const float*)d_in[5];
    const float* bv  = (const float*)d_in[6];
    const float* wo  = (const float*)d_in[7];
    const float* bo  = (const float*)d_in[8];
    const float* w1  = (const float*)d_in[9];
    const float* b1  = (const float*)d_in[10];
    const float* w2  = (const float*)d_in[11];
    const float* b2  = (const float*)d_in[12];
    const float* g1  = (const float*)d_in[13];
    const float* be1 = (const float*)d_in[14];
    const float* g2  = (const float*)d_in[15];
    const float* be2 = (const float*)d_in[16];
    float* out = (float*)d_out;
    char* ws = (char*)d_ws;
    const size_t MB = 1u << 20;

    // layout (185 MB total, with aliasing):
    u16* xb      = (u16*)(ws + 0);        // 16 MB (dead after QKV gemm)
    u16* wqkvT   = (u16*)(ws + 16 * MB);  // 6 MB [wq^T*QSCALE | wk^T | wv^T]
    u16* woT     = (u16*)(ws + 22 * MB);  // 2 MB
    u16* w1T     = (u16*)(ws + 24 * MB);  // 8 MB
    u16* w2T     = (u16*)(ws + 32 * MB);  // 8 MB
    float* qkvb  = (float*)(ws + 40 * MB);// 12 KB
    u16* qkv     = (u16*)(ws + 41 * MB);  // 48 MB (dead after attn)
    u16* vtb     = (u16*)(ws + 89 * MB);  // 16 MB (dead after attn)
    u16* ctxb    = (u16*)(ws + 105 * MB); // 16 MB
    float* attn_out = (float*)(ws + 121 * MB); // 32 MB (dead after add_ln1)
    float* out1     = (float*)(ws + 153 * MB); // 32 MB
    u16* out1b   = (u16*)(ws + 0);        // 16 MB, aliases dead xb
    u16* hidden  = (u16*)(ws + 41 * MB);  // 64 MB, aliases dead qkv+vtb after attn
    float* ffn2out = (float*)(ws + 121 * MB); // 32 MB, aliases dead attn_out

    // prep: cast + ALL weight transposes + bias concat in ONE launch
    prep<<<20492, 256, 0, stream>>>(x, xb, wq, wk, wv, wo, wqkvT, woT,
                                    w1, w1T, w2, w2T, bq, bk, bv, qkvb);

    // fused QKV projection: 256x128 tiles, grid (24,32) = 768 = 3 exact device
    // passes (the 256-wide tile's 384-block grid was 1.5 passes -> 1/3 idle)
    gemm256b<<<dim3(24, 32), 512, 0, stream>>>(xb, wqkvT, qkvb, nullptr, qkv,
                                               B_ * S_, QKVS, D_, 0);
    transpose_v<<<dim3(S_ / 32, DH_ / 32, B_ * H_), dim3(32, 8), 0, stream>>>(qkv, vtb);

    // attention (flash-style, 64 q/wave, shared frag reads, KVBLK=64)
    attn_kernel<<<dim3(B_ * H_, S_ / 256), 256, 0, stream>>>(qkv, vtb, ctxb);

    // output projection: 256x128 tiles, grid (8,32) = 256 blocks = 1 exact pass
    gemm256b<<<dim3(8, 32), 512, 0, stream>>>(ctxb, woT, bo, attn_out, nullptr,
                                              B_ * S_, D_, D_, 0);
    add_ln<<<B_ * S_, 256, 0, stream>>>(x, attn_out, g1, be1, out1, out1b);

    // FFN
    gemm256<<<dim3(16, 32), 512, 0, stream>>>(out1b, w1T, b1, nullptr, hidden,
                                              B_ * S_, F_, D_, 1);
    gemm256b<<<dim3(8, 32), 512, 0, stream>>>(hidden, w2T, b2, ffn2out, nullptr,
                                              B_ * S_, D_, F_, 0);
    add_ln<<<B_ * S_, 256, 0, stream>>>(out1, ffn2out, g2, be2, out, nullptr);
}